// Round 3
// baseline (458.709 us; speedup 1.0000x reference)
//
#include <hip/hip_runtime.h>
#include <hip/hip_bf16.h>

// Problem dims
#define DM    2048
#define SEQ   2048
#define NB    2
#define NH    16
#define NKVH  4
#define HD    128
#define NQKV  3072   // 2048 q cols + 1024 kv cols
#define MROWS 4096   // B*S
#define KVB   64

using f32x4  = __attribute__((ext_vector_type(4))) float;
using short8 = __attribute__((ext_vector_type(8))) short;
using ushort8 = __attribute__((ext_vector_type(8))) unsigned short;

static __device__ __forceinline__ unsigned short f2bf(float f) {
  __hip_bfloat16 h = __float2bfloat16(f);
  return *reinterpret_cast<unsigned short*>(&h);
}
static __device__ __forceinline__ float bf2f(unsigned short u) {
  union { unsigned int i; float f; } v; v.i = ((unsigned int)u) << 16; return v.f;
}

// async global->LDS, 16B per lane; LDS dest is wave-uniform base + lane*16
typedef __attribute__((address_space(1))) const unsigned char as1_c;
typedef __attribute__((address_space(3))) unsigned char as3_c;
static __device__ __forceinline__ void gload_lds16(const void* g, void* l) {
  __builtin_amdgcn_global_load_lds((as1_c*)g, (as3_c*)l, 16, 0, 0);
}

// ---------------- trig table: tbl[p][d] = (cos, sin)(p / 10000^(d/64)) ----------------

__global__ void build_trig(float2* __restrict__ tbl) {
  int i = blockIdx.x * 256 + threadIdx.x;   // 2048*64
  int p = i >> 6, d = i & 63;
  float inv_ts = powf(10000.0f, -(float)d * (1.0f / 64.0f));
  float ang = (float)p * inv_ts;
  float sn, cs;
  sincosf(ang, &sn, &cs);
  tbl[i] = make_float2(cs, sn);
}

// ---------------- elementwise converts / transposes ----------------

__global__ void f32_to_bf16_vec(const float* __restrict__ src, unsigned short* __restrict__ dst, int n4) {
  int i = blockIdx.x * blockDim.x + threadIdx.x;
  if (i < n4) {
    float4 v = reinterpret_cast<const float4*>(src)[i];
    ushort4 o;
    o.x = f2bf(v.x); o.y = f2bf(v.y); o.z = f2bf(v.z); o.w = f2bf(v.w);
    reinterpret_cast<ushort4*>(dst)[i] = o;
  }
}

// One kernel for all three weight transposes: dst[n][k] = bf16(src[k][n]), K=2048.
__global__ void transpose_all(const float* __restrict__ wq, const float* __restrict__ wkv,
                              const float* __restrict__ wo,
                              unsigned short* __restrict__ WqkvT, unsigned short* __restrict__ WoT) {
  int bx = blockIdx.x;
  const float* src; unsigned short* dst; int N;
  if (bx < 64)       { src = wq;  dst = WqkvT;                         N = 2048; }
  else if (bx < 96)  { src = wkv; dst = WqkvT + (size_t)2048 * DM;     N = 1024; bx -= 64; }
  else               { src = wo;  dst = WoT;                           N = 2048; bx -= 96; }
  __shared__ float t[32][33];
  int n0 = bx * 32, k0 = blockIdx.y * 32;
  int tx = threadIdx.x, ty = threadIdx.y;  // 32 x 8
  for (int j = 0; j < 4; j++)
    t[ty + j * 8][tx] = src[(size_t)(k0 + ty + j * 8) * N + n0 + tx];
  __syncthreads();
  for (int j = 0; j < 4; j++)
    dst[(size_t)(n0 + ty + j * 8) * DM + k0 + tx] = f2bf(t[tx][ty + j * 8]);
}

__global__ void bias_concat(const float* __restrict__ bq, const float* __restrict__ bkv, float* __restrict__ o) {
  int i = blockIdx.x * 256 + threadIdx.x;
  if (i < NQKV) o[i] = (i < DM) ? bq[i] : bkv[i - DM];
}

// ------------- QKV GEMM (m97 structure) with fused RoPE/scatter epilogue -------------
// Each N-tile (128 cols) is exactly one head slice: tiles 0-15 = Q heads, then per kv
// head: tile (16+2k) = K, tile (17+2k) = V.

__global__ __launch_bounds__(256) void gemm_qkv(const unsigned short* __restrict__ A,
                                                const unsigned short* __restrict__ Bt,
                                                const float* __restrict__ bias,
                                                const int* __restrict__ seq_pos,
                                                const float2* __restrict__ tbl,
                                                unsigned short* __restrict__ Qo,
                                                unsigned short* __restrict__ Ko,
                                                unsigned short* __restrict__ Vo) {
  __shared__ __align__(16) unsigned short smem[128 * 136];  // K-loop: la=[0,8K), lb=[8K,16K) shorts; epilogue: C tile [128][136]
  unsigned short* la = smem;
  unsigned short* lb = smem + 128 * 64;
  const int K = DM;
  int tid = threadIdx.x, lane = tid & 63, w = tid >> 6;
  int wr = w >> 1, wc = w & 1, lg = lane >> 4, ln = lane & 15;
  int m0 = blockIdx.y * 128, n0 = blockIdx.x * 128;

  f32x4 acc[4][4];
  for (int mi = 0; mi < 4; mi++)
    for (int ni = 0; ni < 4; ni++) acc[mi][ni] = (f32x4){0, 0, 0, 0};

  int srow = lane >> 3;         // 0..7
  int scol = (lane & 7) * 8;
  const unsigned short* ga = A + (size_t)(m0 + w * 32 + srow) * K + scol;
  const unsigned short* gb = Bt + (size_t)(n0 + w * 32 + srow) * K + scol;
  unsigned short* lab = &la[(w * 32) * 64];
  unsigned short* lbb = &lb[(w * 32) * 64];

  for (int kt = 0; kt < K; kt += 64) {
#pragma unroll
    for (int i = 0; i < 4; i++) {
      gload_lds16(ga + (size_t)i * 8 * K + kt, lab + i * 8 * 64);
      gload_lds16(gb + (size_t)i * 8 * K + kt, lbb + i * 8 * 64);
    }
    __syncthreads();
#pragma unroll
    for (int kk = 0; kk < 64; kk += 32) {
      short8 af[4], bfr[4];
#pragma unroll
      for (int mi = 0; mi < 4; mi++)
        af[mi] = *reinterpret_cast<const short8*>(&la[(wr * 64 + mi * 16 + ln) * 64 + kk + lg * 8]);
#pragma unroll
      for (int ni = 0; ni < 4; ni++)
        bfr[ni] = *reinterpret_cast<const short8*>(&lb[(wc * 64 + ni * 16 + ln) * 64 + kk + lg * 8]);
#pragma unroll
      for (int mi = 0; mi < 4; mi++)
#pragma unroll
        for (int ni = 0; ni < 4; ni++)
          acc[mi][ni] = __builtin_amdgcn_mfma_f32_16x16x32_bf16(af[mi], bfr[ni], acc[mi][ni], 0, 0, 0);
    }
    __syncthreads();
  }

  // ---- epilogue: C tile -> LDS (bf16, +bias), then RoPE/scatter ----
  __syncthreads();   // re-purpose smem
#pragma unroll
  for (int mi = 0; mi < 4; mi++) {
    int row = wr * 64 + mi * 16 + lg * 4;
#pragma unroll
    for (int ni = 0; ni < 4; ni++) {
      int col = wc * 64 + ni * 16 + ln;
      float bv = bias[n0 + col];
#pragma unroll
      for (int r4 = 0; r4 < 4; r4++)
        smem[(row + r4) * 136 + col] = f2bf(acc[mi][ni][r4] + bv);
    }
  }
  __syncthreads();

  int nt = blockIdx.x;
  int b = m0 >> 11, s0 = m0 & (SEQ - 1);

  if (nt < 16 || !((nt - 16) & 1)) {
    // Q head (nt<16) or K head: apply RoPE
    float scale; unsigned short* dst;
    if (nt < 16) { scale = 0.08838834764831845f; dst = Qo + ((size_t)(b * NH + nt) * SEQ) * HD; }
    else         { scale = 1.0f; dst = Ko + ((size_t)(b * NKVH + ((nt - 16) >> 1)) * SEQ) * HD; }
    int sl = tid >> 1, dh = (tid & 1) * 32;
    int sg = s0 + sl;
    int pos = seq_pos[b * SEQ + sg];
    const float2* tp = tbl + pos * 64 + dh;
    ushort8 fb[4], sb2[4];
#pragma unroll
    for (int j = 0; j < 32; j++) {
      float x1 = bf2f(smem[sl * 136 + dh + j]);
      float x2 = bf2f(smem[sl * 136 + dh + j + 64]);
      float2 cs = tp[j];
      fb[j >> 3][j & 7]  = f2bf((x1 * cs.x - x2 * cs.y) * scale);
      sb2[j >> 3][j & 7] = f2bf((x2 * cs.x + x1 * cs.y) * scale);
    }
    unsigned short* dp = dst + (size_t)sg * HD + dh;
#pragma unroll
    for (int k = 0; k < 4; k++) {
      *reinterpret_cast<ushort8*>(dp + k * 8)      = fb[k];
      *reinterpret_cast<ushort8*>(dp + 64 + k * 8) = sb2[k];
    }
  } else {
    // V head: transpose to Vt[b][kvh][d][s]
    int kvh = (nt - 16) >> 1;
    int d = tid >> 1, sh = (tid & 1) * 64;
    ushort8 vb[8];
#pragma unroll
    for (int j = 0; j < 64; j++)
      vb[j >> 3][j & 7] = smem[(sh + j) * 136 + d];
    unsigned short* dp = Vo + ((size_t)(b * NKVH + kvh) * HD + d) * SEQ + s0 + sh;
#pragma unroll
    for (int k = 0; k < 8; k++)
      *reinterpret_cast<ushort8*>(dp + k * 8) = vb[k];
  }
}

// ------------- bf16 MFMA GEMM (m97 structure): C = A * Bt^T + bias (f32 out) -------------

__global__ __launch_bounds__(256) void gemm_bt(const unsigned short* __restrict__ A,
                                               const unsigned short* __restrict__ Bt,
                                               const float* __restrict__ bias,
                                               float* __restrict__ C, int M, int N, int K) {
  __shared__ __align__(16) unsigned short la[128 * 64];
  __shared__ __align__(16) unsigned short lb[128 * 64];
  int tid = threadIdx.x, lane = tid & 63, w = tid >> 6;
  int wr = w >> 1, wc = w & 1, lg = lane >> 4, ln = lane & 15;
  int m0 = blockIdx.y * 128, n0 = blockIdx.x * 128;

  f32x4 acc[4][4];
  for (int mi = 0; mi < 4; mi++)
    for (int ni = 0; ni < 4; ni++) acc[mi][ni] = (f32x4){0, 0, 0, 0};

  int srow = lane >> 3, scol = (lane & 7) * 8;
  const unsigned short* ga = A + (size_t)(m0 + w * 32 + srow) * K + scol;
  const unsigned short* gb = Bt + (size_t)(n0 + w * 32 + srow) * K + scol;
  unsigned short* lab = &la[(w * 32) * 64];
  unsigned short* lbb = &lb[(w * 32) * 64];

  for (int kt = 0; kt < K; kt += 64) {
#pragma unroll
    for (int i = 0; i < 4; i++) {
      gload_lds16(ga + (size_t)i * 8 * K + kt, lab + i * 8 * 64);
      gload_lds16(gb + (size_t)i * 8 * K + kt, lbb + i * 8 * 64);
    }
    __syncthreads();
#pragma unroll
    for (int kk = 0; kk < 64; kk += 32) {
      short8 af[4], bfr[4];
#pragma unroll
      for (int mi = 0; mi < 4; mi++)
        af[mi] = *reinterpret_cast<const short8*>(&la[(wr * 64 + mi * 16 + ln) * 64 + kk + lg * 8]);
#pragma unroll
      for (int ni = 0; ni < 4; ni++)
        bfr[ni] = *reinterpret_cast<const short8*>(&lb[(wc * 64 + ni * 16 + ln) * 64 + kk + lg * 8]);
#pragma unroll
      for (int mi = 0; mi < 4; mi++)
#pragma unroll
        for (int ni = 0; ni < 4; ni++)
          acc[mi][ni] = __builtin_amdgcn_mfma_f32_16x16x32_bf16(af[mi], bfr[ni], acc[mi][ni], 0, 0, 0);
    }
    __syncthreads();
  }
  for (int mi = 0; mi < 4; mi++) {
    int mrow = m0 + wr * 64 + mi * 16 + lg * 4;
    for (int ni = 0; ni < 4; ni++) {
      int n = n0 + wc * 64 + ni * 16 + ln;
      float bv = bias[n];
      for (int r4 = 0; r4 < 4; r4++)
        C[(size_t)(mrow + r4) * N + n] = acc[mi][ni][r4] + bv;
    }
  }
}

// ---------------- causal GQA flash attention v3 ----------------
// grid (S/128, B*NH): block handles q-tiles {bx, 31-bx} (33 KV iters each).
// 4 waves x 16 q-rows, KVBLK=64, XOR-swizzled LDS, async reg prefetch of next
// K/V tile, row-sums via ones-column MFMA.

__global__ __launch_bounds__(256) void flash_attn(const unsigned short* __restrict__ Q,
                                                  const unsigned short* __restrict__ Kr,
                                                  const unsigned short* __restrict__ Vt,
                                                  const int* __restrict__ seq_pos,
                                                  unsigned short* __restrict__ X) {
  __shared__ __align__(16) unsigned short lds_k[64 * 128];   // [kv][d] swizzled
  __shared__ __align__(16) unsigned short lds_v[128 * 64];   // [d][kv] swizzled
  __shared__ __align__(16) unsigned short lds_p[4][16 * 64]; // per-wave P swizzled
  int tid = threadIdx.x, lane = tid & 63, w = tid >> 6;
  int bh = blockIdx.y, b = bh >> 4, h = bh & 15, kvh = h >> 2;
  int lg = lane >> 4, ln = lane & 15;

  const unsigned short* kbase = Kr + ((size_t)(b * NKVH + kvh)) * SEQ * HD;
  const unsigned short* vbase = Vt + ((size_t)(b * NKVH + kvh)) * HD * SEQ;

  int krow = tid >> 2, kc0 = (tid & 3) * 32;  // K: 64 rows, 4x16B/thread
  int ksw = (krow & 7) << 4;
  int vrow = tid >> 1, vc0 = (tid & 1) * 32;  // V: 128 rows, 4x16B/thread
  int vsw = (vrow & 7) << 4;
  const unsigned short* gk0 = kbase + (size_t)krow * HD + kc0;
  const unsigned short* gv0 = vbase + (size_t)vrow * SEQ + vc0;

  const short8 ones = {0x3F80, 0x3F80, 0x3F80, 0x3F80, 0x3F80, 0x3F80, 0x3F80, 0x3F80};

  uint4 kreg[4], vreg[4];

  for (int pass = 0; pass < 2; pass++) {
    int qtile = (pass == 0) ? (int)blockIdx.x : (SEQ / 64 - 1 - (int)blockIdx.x);
    int qblk = qtile * 64;
    int q0w = qblk + w * 16;

    int pmax = seq_pos[b * SEQ + qblk + lane];
    for (int o = 32; o; o >>= 1) { int t2 = __shfl_xor(pmax, o); pmax = pmax > t2 ? pmax : t2; }
    int ntiles = (pmax + KVB) >> 6;
    if (ntiles > SEQ / KVB) ntiles = SEQ / KVB;

    int pos_r[4];
    for (int r = 0; r < 4; r++) pos_r[r] = seq_pos[b * SEQ + q0w + lg * 4 + r];

    short8 qf[4];
    {
      const unsigned short* qp = Q + ((size_t)((b * NH + h) * SEQ + q0w + ln)) * HD;
      for (int c = 0; c < 4; c++) qf[c] = *reinterpret_cast<const short8*>(qp + c * 32 + lg * 8);
    }

    f32x4 acc[8];
    for (int dt = 0; dt < 8; dt++) acc[dt] = (f32x4){0, 0, 0, 0};
    f32x4 lacc = (f32x4){0, 0, 0, 0};
    float m_r[4] = {-1e30f, -1e30f, -1e30f, -1e30f};

    // prologue: load tile 0 into regs
#pragma unroll
    for (int j = 0; j < 4; j++) {
      kreg[j] = *reinterpret_cast<const uint4*>(gk0 + j * 8);
      vreg[j] = *reinterpret_cast<const uint4*>(gv0 + j * 8);
    }

    for (int t = 0; t < ntiles; t++) {
      int kv0 = t * KVB;
      __syncthreads();   // previous tile's LDS reads complete
      {
        char* lk = (char*)lds_k + krow * 256;
        char* lv = (char*)lds_v + vrow * 128;
#pragma unroll
        for (int j = 0; j < 4; j++) {
          *reinterpret_cast<uint4*>(lk + ((kc0 * 2 + j * 16) ^ ksw)) = kreg[j];
          *reinterpret_cast<uint4*>(lv + ((vc0 * 2 + j * 16) ^ vsw)) = vreg[j];
        }
      }
      // async prefetch of next tile (lands during compute below)
      if (t + 1 < ntiles) {
        int nkv = kv0 + KVB;
#pragma unroll
        for (int j = 0; j < 4; j++) {
          kreg[j] = *reinterpret_cast<const uint4*>(gk0 + (size_t)nkv * HD + j * 8);
          vreg[j] = *reinterpret_cast<const uint4*>(gv0 + nkv + j * 8);
        }
      }
      __syncthreads();

      // QK^T: S tile 16(q) x 64(kv)
      f32x4 sa[4];
#pragma unroll
      for (int ct = 0; ct < 4; ct++) {
        sa[ct] = (f32x4){0, 0, 0, 0};
        int row = ct * 16 + ln;
        const char* kr0 = (const char*)lds_k + row * 256;
        int sw = (row & 7) << 4;
#pragma unroll
        for (int c = 0; c < 4; c++) {
          short8 kf = *reinterpret_cast<const short8*>(kr0 + ((c * 64 + lg * 16) ^ sw));
          sa[ct] = __builtin_amdgcn_mfma_f32_16x16x32_bf16(qf[c], kf, sa[ct], 0, 0, 0);
        }
      }

      // online softmax: mask, row-max via shfl, exp; row-sum comes from ones-MFMA
      float p[4][4], corr[4];
#pragma unroll
      for (int r = 0; r < 4; r++) {
        int kv = kv0 + ln;
        float v0 = (kv      <= pos_r[r]) ? sa[0][r] : -1e30f;
        float v1 = (kv + 16 <= pos_r[r]) ? sa[1][r] : -1e30f;
        float v2 = (kv + 32 <= pos_r[r]) ? sa[2][r] : -1e30f;
        float v3 = (kv + 48 <= pos_r[r]) ? sa[3][r] : -1e30f;
        float tmx = fmaxf(fmaxf(v0, v1), fmaxf(v2, v3));
        tmx = fmaxf(tmx, __shfl_xor(tmx, 1));
        tmx = fmaxf(tmx, __shfl_xor(tmx, 2));
        tmx = fmaxf(tmx, __shfl_xor(tmx, 4));
        tmx = fmaxf(tmx, __shfl_xor(tmx, 8));
        float nm = fmaxf(m_r[r], tmx);
        corr[r] = __expf(m_r[r] - nm);
        p[0][r] = __expf(v0 - nm); p[1][r] = __expf(v1 - nm);
        p[2][r] = __expf(v2 - nm); p[3][r] = __expf(v3 - nm);
        m_r[r] = nm;
      }

      // P -> per-wave swizzled LDS
      {
        char* pw = (char*)lds_p[w];
#pragma unroll
        for (int r = 0; r < 4; r++) {
          int row = lg * 4 + r;
          int sw2 = (row & 7) << 4;
          char* pr = pw + row * 128;
#pragma unroll
          for (int ct = 0; ct < 4; ct++)
            *reinterpret_cast<unsigned short*>(pr + (((ct * 16 + ln) * 2) ^ sw2)) = f2bf(p[ct][r]);
        }
      }

      // rescale accumulators while P writes land
#pragma unroll
      for (int dt = 0; dt < 8; dt++)
#pragma unroll
        for (int r = 0; r < 4; r++) acc[dt][r] *= corr[r];
#pragma unroll
      for (int r = 0; r < 4; r++) lacc[r] *= corr[r];

      asm volatile("s_waitcnt lgkmcnt(0)" ::: "memory");
      __builtin_amdgcn_sched_barrier(0);
      short8 pf[2];
      {
        const char* pr = (const char*)lds_p[w] + ln * 128;
        int sw2 = (ln & 7) << 4;
        pf[0] = *reinterpret_cast<const short8*>(pr + ((lg * 16) ^ sw2));
        pf[1] = *reinterpret_cast<const short8*>(pr + ((64 + lg * 16) ^ sw2));
      }

      // PV + row-sum MFMA
#pragma unroll
      for (int dt = 0; dt < 8; dt++) {
        int row = dt * 16 + ln;
        const char* vr0 = (const char*)lds_v + row * 128;
        int sw3 = (row & 7) << 4;
        short8 vf0 = *reinterpret_cast<const short8*>(vr0 + ((lg * 16) ^ sw3));
        short8 vf1 = *reinterpret_cast<const short8*>(vr0 + ((64 + lg * 16) ^ sw3));
        acc[dt] = __builtin_amdgcn_mfma_f32_16x16x32_bf16(pf[0], vf0, acc[dt], 0, 0, 0);
        acc[dt] = __builtin_amdgcn_mfma_f32_16x16x32_bf16(pf[1], vf1, acc[dt], 0, 0, 0);
      }
      lacc = __builtin_amdgcn_mfma_f32_16x16x32_bf16(pf[0], ones, lacc, 0, 0, 0);
      lacc = __builtin_amdgcn_mfma_f32_16x16x32_bf16(pf[1], ones, lacc, 0, 0, 0);
    }

    // epilogue
    for (int r = 0; r < 4; r++) {
      float inv = lacc[r] > 0.0f ? 1.0f / lacc[r] : 0.0f;
      int qrow = q0w + lg * 4 + r;
      unsigned short* xp = X + ((size_t)(b * SEQ + qrow)) * DM + h * HD;
      for (int dt = 0; dt < 8; dt++) xp[dt * 16 + ln] = f2bf(acc[dt][r] * inv);
    }
  }
}

// ---------------- launch ----------------

extern "C" void kernel_launch(void* const* d_in, const int* in_sizes, int n_in,
                              void* d_out, int out_size, void* d_ws, size_t ws_size,
                              hipStream_t stream) {
  const float* inputs  = (const float*)d_in[0];
  const int*   seq_pos = (const int*)d_in[1];
  const float* wq  = (const float*)d_in[2];
  const float* bq  = (const float*)d_in[3];
  const float* wkv = (const float*)d_in[4];
  const float* bkv = (const float*)d_in[5];
  const float* wo  = (const float*)d_in[6];
  const float* bo  = (const float*)d_in[7];
  float* out = (float*)d_out;

  char* ws = (char*)d_ws;
  unsigned short* Abf     = (unsigned short*)(ws + 0);          // 16.78 MB
  unsigned short* WqkvT   = (unsigned short*)(ws + 16777216);   // 12.58 MB
  unsigned short* WoT     = (unsigned short*)(ws + 29360128);   // 8.39 MB
  float*          biasqkv = (float*)(ws + 37748736);            // 12 KB
  float2*         tbl     = (float2*)(ws + 37761024);           // 1 MB
  unsigned short* Qr      = (unsigned short*)(ws + 38809600);   // 16.78 MB
  unsigned short* Kr      = (unsigned short*)(ws + 55586816);   // 4.19 MB
  unsigned short* Vt      = (unsigned short*)(ws + 59781120);   // 4.19 MB
  unsigned short* Xb      = (unsigned short*)(ws + 63975424);   // 16.78 MB (end ~80.8 MB)

  build_trig<<<512, 256, 0, stream>>>(tbl);
  f32_to_bf16_vec<<<8192, 256, 0, stream>>>(inputs, Abf, (NB * SEQ * DM) / 4);
  transpose_all<<<dim3(160, 64), dim3(32, 8), 0, stream>>>(wq, wkv, wo, WqkvT, WoT);
  bias_concat<<<12, 256, 0, stream>>>(bq, bkv, biasqkv);

  gemm_qkv<<<dim3(NQKV / 128, MROWS / 128), 256, 0, stream>>>(
      Abf, WqkvT, biasqkv, seq_pos, tbl, Qr, Kr, Vt);

  flash_attn<<<dim3(SEQ / 128, NB * NH), 256, 0, stream>>>(Qr, Kr, Vt, seq_pos, Xb);

  gemm_bt<<<dim3(DM / 128, MROWS / 128), 256, 0, stream>>>(
      Xb, WoT, bo, out, MROWS, DM, DM);
}

// Round 4
// 362.322 us; speedup vs baseline: 1.2660x; 1.2660x over previous
//
#include <hip/hip_runtime.h>
#include <hip/hip_bf16.h>

// Problem dims
#define DM    2048
#define SEQ   2048
#define NB    2
#define NH    16
#define NKVH  4
#define HD    128
#define NQKV  3072   // 2048 q cols + 1024 kv cols
#define MROWS 4096   // B*S
#define KVB   64

using f32x4  = __attribute__((ext_vector_type(4))) float;
using short8 = __attribute__((ext_vector_type(8))) short;
using ushort8 = __attribute__((ext_vector_type(8))) unsigned short;

static __device__ __forceinline__ unsigned short f2bf(float f) {
  __hip_bfloat16 h = __float2bfloat16(f);
  return *reinterpret_cast<unsigned short*>(&h);
}
static __device__ __forceinline__ float bf2f(unsigned short u) {
  union { unsigned int i; float f; } v; v.i = ((unsigned int)u) << 16; return v.f;
}

// async global->LDS, 16B per lane; LDS dest is wave-uniform base + lane*16
typedef __attribute__((address_space(1))) const unsigned char as1_c;
typedef __attribute__((address_space(3))) unsigned char as3_c;
static __device__ __forceinline__ void gload_lds16(const void* g, void* l) {
  __builtin_amdgcn_global_load_lds((as1_c*)g, (as3_c*)l, 16, 0, 0);
}

// ---------------- trig table: tbl[p][d] = (cos, sin)(p / 10000^(d/64)) ----------------

__global__ void build_trig(float2* __restrict__ tbl) {
  int i = blockIdx.x * 256 + threadIdx.x;   // 2048*64
  int p = i >> 6, d = i & 63;
  float inv_ts = powf(10000.0f, -(float)d * (1.0f / 64.0f));
  float ang = (float)p * inv_ts;
  float sn, cs;
  sincosf(ang, &sn, &cs);
  tbl[i] = make_float2(cs, sn);
}

// ---------------- elementwise converts / transposes ----------------

__global__ void f32_to_bf16_vec(const float* __restrict__ src, unsigned short* __restrict__ dst, int n4) {
  int i = blockIdx.x * blockDim.x + threadIdx.x;
  if (i < n4) {
    float4 v = reinterpret_cast<const float4*>(src)[i];
    ushort4 o;
    o.x = f2bf(v.x); o.y = f2bf(v.y); o.z = f2bf(v.z); o.w = f2bf(v.w);
    reinterpret_cast<ushort4*>(dst)[i] = o;
  }
}

// One kernel for all three weight transposes: dst[n][k] = bf16(src[k][n]), K=2048.
__global__ void transpose_all(const float* __restrict__ wq, const float* __restrict__ wkv,
                              const float* __restrict__ wo,
                              unsigned short* __restrict__ WqkvT, unsigned short* __restrict__ WoT) {
  int bx = blockIdx.x;
  const float* src; unsigned short* dst; int N;
  if (bx < 64)       { src = wq;  dst = WqkvT;                         N = 2048; }
  else if (bx < 96)  { src = wkv; dst = WqkvT + (size_t)2048 * DM;     N = 1024; bx -= 64; }
  else               { src = wo;  dst = WoT;                           N = 2048; bx -= 96; }
  __shared__ float t[32][33];
  int n0 = bx * 32, k0 = blockIdx.y * 32;
  int tx = threadIdx.x, ty = threadIdx.y;  // 32 x 8
  for (int j = 0; j < 4; j++)
    t[ty + j * 8][tx] = src[(size_t)(k0 + ty + j * 8) * N + n0 + tx];
  __syncthreads();
  for (int j = 0; j < 4; j++)
    dst[(size_t)(n0 + ty + j * 8) * DM + k0 + tx] = f2bf(t[tx][ty + j * 8]);
}

__global__ void bias_concat(const float* __restrict__ bq, const float* __restrict__ bkv, float* __restrict__ o) {
  int i = blockIdx.x * 256 + threadIdx.x;
  if (i < NQKV) o[i] = (i < DM) ? bq[i] : bkv[i - DM];
}

// ------------- QKV GEMM (m97 structure) with fused RoPE/scatter epilogue -------------
// Each N-tile (128 cols) is exactly one head slice: tiles 0-15 = Q heads, then per kv
// head: tile (16+2k) = K, tile (17+2k) = V.

__global__ __launch_bounds__(256) void gemm_qkv(const unsigned short* __restrict__ A,
                                                const unsigned short* __restrict__ Bt,
                                                const float* __restrict__ bias,
                                                const int* __restrict__ seq_pos,
                                                const float2* __restrict__ tbl,
                                                unsigned short* __restrict__ Qo,
                                                unsigned short* __restrict__ Ko,
                                                unsigned short* __restrict__ Vo) {
  __shared__ __align__(16) unsigned short smem[128 * 136];  // K-loop: la/lb; epilogue: C tile [128][136]
  unsigned short* la = smem;
  unsigned short* lb = smem + 128 * 64;
  const int K = DM;
  int tid = threadIdx.x, lane = tid & 63, w = tid >> 6;
  int wr = w >> 1, wc = w & 1, lg = lane >> 4, ln = lane & 15;
  int m0 = blockIdx.y * 128, n0 = blockIdx.x * 128;

  f32x4 acc[4][4];
  for (int mi = 0; mi < 4; mi++)
    for (int ni = 0; ni < 4; ni++) acc[mi][ni] = (f32x4){0, 0, 0, 0};

  int srow = lane >> 3;         // 0..7
  int scol = (lane & 7) * 8;
  const unsigned short* ga = A + (size_t)(m0 + w * 32 + srow) * K + scol;
  const unsigned short* gb = Bt + (size_t)(n0 + w * 32 + srow) * K + scol;
  unsigned short* lab = &la[(w * 32) * 64];
  unsigned short* lbb = &lb[(w * 32) * 64];

  for (int kt = 0; kt < K; kt += 64) {
#pragma unroll
    for (int i = 0; i < 4; i++) {
      gload_lds16(ga + (size_t)i * 8 * K + kt, lab + i * 8 * 64);
      gload_lds16(gb + (size_t)i * 8 * K + kt, lbb + i * 8 * 64);
    }
    __syncthreads();
#pragma unroll
    for (int kk = 0; kk < 64; kk += 32) {
      short8 af[4], bfr[4];
#pragma unroll
      for (int mi = 0; mi < 4; mi++)
        af[mi] = *reinterpret_cast<const short8*>(&la[(wr * 64 + mi * 16 + ln) * 64 + kk + lg * 8]);
#pragma unroll
      for (int ni = 0; ni < 4; ni++)
        bfr[ni] = *reinterpret_cast<const short8*>(&lb[(wc * 64 + ni * 16 + ln) * 64 + kk + lg * 8]);
#pragma unroll
      for (int mi = 0; mi < 4; mi++)
#pragma unroll
        for (int ni = 0; ni < 4; ni++)
          acc[mi][ni] = __builtin_amdgcn_mfma_f32_16x16x32_bf16(af[mi], bfr[ni], acc[mi][ni], 0, 0, 0);
    }
    __syncthreads();
  }

  // ---- epilogue: C tile -> LDS (bf16, +bias), then RoPE/scatter ----
  __syncthreads();   // re-purpose smem
#pragma unroll
  for (int mi = 0; mi < 4; mi++) {
    int row = wr * 64 + mi * 16 + lg * 4;
#pragma unroll
    for (int ni = 0; ni < 4; ni++) {
      int col = wc * 64 + ni * 16 + ln;
      float bv = bias[n0 + col];
#pragma unroll
      for (int r4 = 0; r4 < 4; r4++)
        smem[(row + r4) * 136 + col] = f2bf(acc[mi][ni][r4] + bv);
    }
  }
  __syncthreads();

  int nt = blockIdx.x;
  int b = m0 >> 11, s0 = m0 & (SEQ - 1);

  if (nt < 16 || !((nt - 16) & 1)) {
    // Q head (nt<16) or K head: apply RoPE
    float scale; unsigned short* dst;
    if (nt < 16) { scale = 0.08838834764831845f; dst = Qo + ((size_t)(b * NH + nt) * SEQ) * HD; }
    else         { scale = 1.0f; dst = Ko + ((size_t)(b * NKVH + ((nt - 16) >> 1)) * SEQ) * HD; }
    int sl = tid >> 1, dh = (tid & 1) * 32;
    int sg = s0 + sl;
    int pos = seq_pos[b * SEQ + sg];
    const float2* tp = tbl + pos * 64 + dh;
    ushort8 fb[4], sb2[4];
#pragma unroll
    for (int j = 0; j < 32; j++) {
      float x1 = bf2f(smem[sl * 136 + dh + j]);
      float x2 = bf2f(smem[sl * 136 + dh + j + 64]);
      float2 cs = tp[j];
      fb[j >> 3][j & 7]  = f2bf((x1 * cs.x - x2 * cs.y) * scale);
      sb2[j >> 3][j & 7] = f2bf((x2 * cs.x + x1 * cs.y) * scale);
    }
    unsigned short* dp = dst + (size_t)sg * HD + dh;
#pragma unroll
    for (int k = 0; k < 4; k++) {
      *reinterpret_cast<ushort8*>(dp + k * 8)      = fb[k];
      *reinterpret_cast<ushort8*>(dp + 64 + k * 8) = sb2[k];
    }
  } else {
    // V head: transpose to Vt[b][kvh][d][s]
    int kvh = (nt - 16) >> 1;
    int d = tid >> 1, sh = (tid & 1) * 64;
    ushort8 vb[8];
#pragma unroll
    for (int j = 0; j < 64; j++)
      vb[j >> 3][j & 7] = smem[(sh + j) * 136 + d];
    unsigned short* dp = Vo + ((size_t)(b * NKVH + kvh) * HD + d) * SEQ + s0 + sh;
#pragma unroll
    for (int k = 0; k < 8; k++)
      *reinterpret_cast<ushort8*>(dp + k * 8) = vb[k];
  }
}

// ------------- bf16 MFMA GEMM (m97 structure): C = A * Bt^T + bias (f32 out) -------------

__global__ __launch_bounds__(256) void gemm_bt(const unsigned short* __restrict__ A,
                                               const unsigned short* __restrict__ Bt,
                                               const float* __restrict__ bias,
                                               float* __restrict__ C, int M, int N, int K) {
  __shared__ __align__(16) unsigned short la[128 * 64];
  __shared__ __align__(16) unsigned short lb[128 * 64];
  int tid = threadIdx.x, lane = tid & 63, w = tid >> 6;
  int wr = w >> 1, wc = w & 1, lg = lane >> 4, ln = lane & 15;
  int m0 = blockIdx.y * 128, n0 = blockIdx.x * 128;

  f32x4 acc[4][4];
  for (int mi = 0; mi < 4; mi++)
    for (int ni = 0; ni < 4; ni++) acc[mi][ni] = (f32x4){0, 0, 0, 0};

  int srow = lane >> 3, scol = (lane & 7) * 8;
  const unsigned short* ga = A + (size_t)(m0 + w * 32 + srow) * K + scol;
  const unsigned short* gb = Bt + (size_t)(n0 + w * 32 + srow) * K + scol;
  unsigned short* lab = &la[(w * 32) * 64];
  unsigned short* lbb = &lb[(w * 32) * 64];

  for (int kt = 0; kt < K; kt += 64) {
#pragma unroll
    for (int i = 0; i < 4; i++) {
      gload_lds16(ga + (size_t)i * 8 * K + kt, lab + i * 8 * 64);
      gload_lds16(gb + (size_t)i * 8 * K + kt, lbb + i * 8 * 64);
    }
    __syncthreads();
#pragma unroll
    for (int kk = 0; kk < 64; kk += 32) {
      short8 af[4], bfr[4];
#pragma unroll
      for (int mi = 0; mi < 4; mi++)
        af[mi] = *reinterpret_cast<const short8*>(&la[(wr * 64 + mi * 16 + ln) * 64 + kk + lg * 8]);
#pragma unroll
      for (int ni = 0; ni < 4; ni++)
        bfr[ni] = *reinterpret_cast<const short8*>(&lb[(wc * 64 + ni * 16 + ln) * 64 + kk + lg * 8]);
#pragma unroll
      for (int mi = 0; mi < 4; mi++)
#pragma unroll
        for (int ni = 0; ni < 4; ni++)
          acc[mi][ni] = __builtin_amdgcn_mfma_f32_16x16x32_bf16(af[mi], bfr[ni], acc[mi][ni], 0, 0, 0);
    }
    __syncthreads();
  }
  for (int mi = 0; mi < 4; mi++) {
    int mrow = m0 + wr * 64 + mi * 16 + lg * 4;
    for (int ni = 0; ni < 4; ni++) {
      int n = n0 + wc * 64 + ni * 16 + ln;
      float bv = bias[n];
      for (int r4 = 0; r4 < 4; r4++)
        C[(size_t)(mrow + r4) * N + n] = acc[mi][ni][r4] + bv;
    }
  }
}

// ---------------- causal GQA flash attention v4 ----------------
// grid (S/128, B*NH): block handles q-tiles {bx, 31-bx} (33 KV iters each).
// 4 waves x 16 q-rows, KVBLK=64. K/V staged via global_load_lds with
// PRE-SWIZZLED per-lane global source (linear LDS dest, XOR-swizzled reads).
// Row-sums via ones-column MFMA.

__global__ __launch_bounds__(256) void flash_attn(const unsigned short* __restrict__ Q,
                                                  const unsigned short* __restrict__ Kr,
                                                  const unsigned short* __restrict__ Vt,
                                                  const int* __restrict__ seq_pos,
                                                  unsigned short* __restrict__ X) {
  __shared__ __align__(16) unsigned short lds_k[64 * 128];   // [kv][d], swizzle via source
  __shared__ __align__(16) unsigned short lds_v[128 * 64];   // [d][kv], swizzle via source
  __shared__ __align__(16) unsigned short lds_p[4][16 * 64]; // per-wave P swizzled
  int tid = threadIdx.x, lane = tid & 63, w = tid >> 6;
  int bh = blockIdx.y, b = bh >> 4, h = bh & 15, kvh = h >> 2;
  int lg = lane >> 4, ln = lane & 15;

  const unsigned short* kbase = Kr + ((size_t)(b * NKVH + kvh)) * SEQ * HD;
  const unsigned short* vbase = Vt + ((size_t)(b * NKVH + kvh)) * HD * SEQ;

  // global_load_lds staging, source pre-swizzled so that
  //   lds_k[row][chunk] = K[kv0+row][chunk ^ (row&7)]   (chunk = 16B unit)
  //   lds_v[row][chunk] = V[row][kv0 + 8*(chunk ^ (row&7)) ...]
  const unsigned short* gks[4]; unsigned short* lks[4];
  const unsigned short* gvs[4]; unsigned short* lvs[4];
#pragma unroll
  for (int i = 0; i < 4; i++) {
    int kr = w * 16 + i * 4 + (lane >> 4);        // K row this lane stages
    int kc = (lane & 15) ^ (kr & 7);              // swizzled source chunk
    gks[i] = kbase + (size_t)kr * HD + kc * 8;
    lks[i] = lds_k + (w * 16 + i * 4) * 128;      // wave-uniform dest
    int vr = w * 32 + i * 8 + (lane >> 3);        // V row (d index)
    int vc = (lane & 7) ^ (vr & 7);
    gvs[i] = vbase + (size_t)vr * SEQ + vc * 8;
    lvs[i] = lds_v + (w * 32 + i * 8) * 64;
  }

  const short8 ones = {0x3F80, 0x3F80, 0x3F80, 0x3F80, 0x3F80, 0x3F80, 0x3F80, 0x3F80};

  for (int pass = 0; pass < 2; pass++) {
    int qtile = (pass == 0) ? (int)blockIdx.x : (SEQ / 64 - 1 - (int)blockIdx.x);
    int qblk = qtile * 64;
    int q0w = qblk + w * 16;

    int pmax = seq_pos[b * SEQ + qblk + lane];
    for (int o = 32; o; o >>= 1) { int t2 = __shfl_xor(pmax, o); pmax = pmax > t2 ? pmax : t2; }
    int ntiles = (pmax + KVB) >> 6;
    if (ntiles > SEQ / KVB) ntiles = SEQ / KVB;

    int pos_r[4];
    for (int r = 0; r < 4; r++) pos_r[r] = seq_pos[b * SEQ + q0w + lg * 4 + r];

    short8 qf[4];
    {
      const unsigned short* qp = Q + ((size_t)((b * NH + h) * SEQ + q0w + ln)) * HD;
      for (int c = 0; c < 4; c++) qf[c] = *reinterpret_cast<const short8*>(qp + c * 32 + lg * 8);
    }

    f32x4 acc[8];
    for (int dt = 0; dt < 8; dt++) acc[dt] = (f32x4){0, 0, 0, 0};
    f32x4 lacc = (f32x4){0, 0, 0, 0};
    float m_r[4] = {-1e30f, -1e30f, -1e30f, -1e30f};

    for (int t = 0; t < ntiles; t++) {
      int kv0 = t * KVB;
      // stage K/V via async global->LDS (no VGPR round-trip, no ds_writes)
#pragma unroll
      for (int i = 0; i < 4; i++) {
        gload_lds16(gks[i] + (size_t)kv0 * HD, lks[i]);
        gload_lds16(gvs[i] + kv0, lvs[i]);
      }
      __syncthreads();   // drains vmcnt; tile visible to all waves

      // QK^T: S tile 16(q) x 64(kv)
      f32x4 sa[4];
#pragma unroll
      for (int ct = 0; ct < 4; ct++) {
        sa[ct] = (f32x4){0, 0, 0, 0};
        int row = ct * 16 + ln;
        const char* kr0 = (const char*)lds_k + row * 256;
        int sw = (row & 7) << 4;
#pragma unroll
        for (int c = 0; c < 4; c++) {
          short8 kf = *reinterpret_cast<const short8*>(kr0 + ((c * 64 + lg * 16) ^ sw));
          sa[ct] = __builtin_amdgcn_mfma_f32_16x16x32_bf16(qf[c], kf, sa[ct], 0, 0, 0);
        }
      }

      // online softmax: mask, row-max via shfl, exp; row-sum via ones-MFMA
      float p[4][4], corr[4];
#pragma unroll
      for (int r = 0; r < 4; r++) {
        int kv = kv0 + ln;
        float v0 = (kv      <= pos_r[r]) ? sa[0][r] : -1e30f;
        float v1 = (kv + 16 <= pos_r[r]) ? sa[1][r] : -1e30f;
        float v2 = (kv + 32 <= pos_r[r]) ? sa[2][r] : -1e30f;
        float v3 = (kv + 48 <= pos_r[r]) ? sa[3][r] : -1e30f;
        float tmx = fmaxf(fmaxf(v0, v1), fmaxf(v2, v3));
        tmx = fmaxf(tmx, __shfl_xor(tmx, 1));
        tmx = fmaxf(tmx, __shfl_xor(tmx, 2));
        tmx = fmaxf(tmx, __shfl_xor(tmx, 4));
        tmx = fmaxf(tmx, __shfl_xor(tmx, 8));
        float nm = fmaxf(m_r[r], tmx);
        corr[r] = __expf(m_r[r] - nm);
        p[0][r] = __expf(v0 - nm); p[1][r] = __expf(v1 - nm);
        p[2][r] = __expf(v2 - nm); p[3][r] = __expf(v3 - nm);
        m_r[r] = nm;
      }

      // P -> per-wave swizzled LDS
      {
        char* pw = (char*)lds_p[w];
#pragma unroll
        for (int r = 0; r < 4; r++) {
          int row = lg * 4 + r;
          int sw2 = (row & 7) << 4;
          char* pr = pw + row * 128;
#pragma unroll
          for (int ct = 0; ct < 4; ct++)
            *reinterpret_cast<unsigned short*>(pr + (((ct * 16 + ln) * 2) ^ sw2)) = f2bf(p[ct][r]);
        }
      }

      // rescale accumulators while P writes land
#pragma unroll
      for (int dt = 0; dt < 8; dt++)
#pragma unroll
        for (int r = 0; r < 4; r++) acc[dt][r] *= corr[r];
#pragma unroll
      for (int r = 0; r < 4; r++) lacc[r] *= corr[r];

      asm volatile("s_waitcnt lgkmcnt(0)" ::: "memory");
      __builtin_amdgcn_sched_barrier(0);
      short8 pf[2];
      {
        const char* pr = (const char*)lds_p[w] + ln * 128;
        int sw2 = (ln & 7) << 4;
        pf[0] = *reinterpret_cast<const short8*>(pr + ((lg * 16) ^ sw2));
        pf[1] = *reinterpret_cast<const short8*>(pr + ((64 + lg * 16) ^ sw2));
      }

      // PV + row-sum MFMA
#pragma unroll
      for (int dt = 0; dt < 8; dt++) {
        int row = dt * 16 + ln;
        const char* vr0 = (const char*)lds_v + row * 128;
        int sw3 = (row & 7) << 4;
        short8 vf0 = *reinterpret_cast<const short8*>(vr0 + ((lg * 16) ^ sw3));
        short8 vf1 = *reinterpret_cast<const short8*>(vr0 + ((64 + lg * 16) ^ sw3));
        acc[dt] = __builtin_amdgcn_mfma_f32_16x16x32_bf16(pf[0], vf0, acc[dt], 0, 0, 0);
        acc[dt] = __builtin_amdgcn_mfma_f32_16x16x32_bf16(pf[1], vf1, acc[dt], 0, 0, 0);
      }
      lacc = __builtin_amdgcn_mfma_f32_16x16x32_bf16(pf[0], ones, lacc, 0, 0, 0);
      lacc = __builtin_amdgcn_mfma_f32_16x16x32_bf16(pf[1], ones, lacc, 0, 0, 0);
      __syncthreads();   // all reads done before next tile's staging overwrites
    }

    // epilogue (registers only)
    for (int r = 0; r < 4; r++) {
      float inv = lacc[r] > 0.0f ? 1.0f / lacc[r] : 0.0f;
      int qrow = q0w + lg * 4 + r;
      unsigned short* xp = X + ((size_t)(b * SEQ + qrow)) * DM + h * HD;
      for (int dt = 0; dt < 8; dt++) xp[dt * 16 + ln] = f2bf(acc[dt][r] * inv);
    }
  }
}

// ---------------- launch ----------------

extern "C" void kernel_launch(void* const* d_in, const int* in_sizes, int n_in,
                              void* d_out, int out_size, void* d_ws, size_t ws_size,
                              hipStream_t stream) {
  const float* inputs  = (const float*)d_in[0];
  const int*   seq_pos = (const int*)d_in[1];
  const float* wq  = (const float*)d_in[2];
  const float* bq  = (const float*)d_in[3];
  const float* wkv = (const float*)d_in[4];
  const float* bkv = (const float*)d_in[5];
  const float* wo  = (const float*)d_in[6];
  const float* bo  = (const float*)d_in[7];
  float* out = (float*)d_out;

  char* ws = (char*)d_ws;
  unsigned short* Abf     = (unsigned short*)(ws + 0);          // 16.78 MB
  unsigned short* WqkvT   = (unsigned short*)(ws + 16777216);   // 12.58 MB
  unsigned short* WoT     = (unsigned short*)(ws + 29360128);   // 8.39 MB
  float*          biasqkv = (float*)(ws + 37748736);            // 12 KB
  float2*         tbl     = (float2*)(ws + 37761024);           // 1 MB
  unsigned short* Qr      = (unsigned short*)(ws + 38809600);   // 16.78 MB
  unsigned short* Kr      = (unsigned short*)(ws + 55586816);   // 4.19 MB
  unsigned short* Vt      = (unsigned short*)(ws + 59781120);   // 4.19 MB
  unsigned short* Xb      = (unsigned short*)(ws + 63975424);   // 16.78 MB (end ~80.8 MB)

  build_trig<<<512, 256, 0, stream>>>(tbl);
  f32_to_bf16_vec<<<8192, 256, 0, stream>>>(inputs, Abf, (NB * SEQ * DM) / 4);
  transpose_all<<<dim3(160, 64), dim3(32, 8), 0, stream>>>(wq, wkv, wo, WqkvT, WoT);
  bias_concat<<<12, 256, 0, stream>>>(bq, bkv, biasqkv);

  gemm_qkv<<<dim3(NQKV / 128, MROWS / 128), 256, 0, stream>>>(
      Abf, WqkvT, biasqkv, seq_pos, tbl, Qr, Kr, Vt);

  flash_attn<<<dim3(SEQ / 128, NB * NH), 256, 0, stream>>>(Qr, Kr, Vt, seq_pos, Xb);

  gemm_bt<<<dim3(DM / 128, MROWS / 128), 256, 0, stream>>>(
      Xb, WoT, bo, out, MROWS, DM, DM);
}

// Round 5
// 314.647 us; speedup vs baseline: 1.4579x; 1.1515x over previous
//
#include <hip/hip_runtime.h>
#include <hip/hip_bf16.h>

// Problem dims
#define DM    2048
#define SEQ   2048
#define NB    2
#define NH    16
#define NKVH  4
#define HD    128
#define NQKV  3072   // 2048 q cols + 1024 kv cols
#define MROWS 4096   // B*S
#define KVB   64
#define QSC   0.08838834764831845f

using f32x4  = __attribute__((ext_vector_type(4))) float;
using short8 = __attribute__((ext_vector_type(8))) short;
using ushort8 = __attribute__((ext_vector_type(8))) unsigned short;

static __device__ __forceinline__ unsigned short f2bf(float f) {
  __hip_bfloat16 h = __float2bfloat16(f);
  return *reinterpret_cast<unsigned short*>(&h);
}
static __device__ __forceinline__ float bf2f(unsigned short u) {
  union { unsigned int i; float f; } v; v.i = ((unsigned int)u) << 16; return v.f;
}

// async global->LDS, 16B per lane; LDS dest is wave-uniform base + lane*16
typedef __attribute__((address_space(1))) const unsigned char as1_c;
typedef __attribute__((address_space(3))) unsigned char as3_c;
static __device__ __forceinline__ void gload_lds16(const void* g, void* l) {
  __builtin_amdgcn_global_load_lds((as1_c*)g, (as3_c*)l, 16, 0, 0);
}

// ---------------- trig table ----------------

__global__ void build_trig(float2* __restrict__ tbl) {
  int i = blockIdx.x * 256 + threadIdx.x;   // 2048*64
  int p = i >> 6, d = i & 63;
  float inv_ts = powf(10000.0f, -(float)d * (1.0f / 64.0f));
  float ang = (float)p * inv_ts;
  float sn, cs;
  sincosf(ang, &sn, &cs);
  tbl[i] = make_float2(cs, sn);
}

// ---------------- elementwise converts / transposes ----------------

__global__ void f32_to_bf16_vec(const float* __restrict__ src, unsigned short* __restrict__ dst, int n4) {
  int i = blockIdx.x * blockDim.x + threadIdx.x;
  if (i < n4) {
    float4 v = reinterpret_cast<const float4*>(src)[i];
    ushort4 o;
    o.x = f2bf(v.x); o.y = f2bf(v.y); o.z = f2bf(v.z); o.w = f2bf(v.w);
    reinterpret_cast<ushort4*>(dst)[i] = o;
  }
}

__global__ void transpose_all(const float* __restrict__ wq, const float* __restrict__ wkv,
                              const float* __restrict__ wo,
                              unsigned short* __restrict__ WqkvT, unsigned short* __restrict__ WoT) {
  int bx = blockIdx.x;
  const float* src; unsigned short* dst; int N;
  if (bx < 64)       { src = wq;  dst = WqkvT;                         N = 2048; }
  else if (bx < 96)  { src = wkv; dst = WqkvT + (size_t)2048 * DM;     N = 1024; bx -= 64; }
  else               { src = wo;  dst = WoT;                           N = 2048; bx -= 96; }
  __shared__ float t[32][33];
  int n0 = bx * 32, k0 = blockIdx.y * 32;
  int tx = threadIdx.x, ty = threadIdx.y;  // 32 x 8
  for (int j = 0; j < 4; j++)
    t[ty + j * 8][tx] = src[(size_t)(k0 + ty + j * 8) * N + n0 + tx];
  __syncthreads();
  for (int j = 0; j < 4; j++)
    dst[(size_t)(n0 + ty + j * 8) * DM + k0 + tx] = f2bf(t[tx][ty + j * 8]);
}

__global__ void bias_concat(const float* __restrict__ bq, const float* __restrict__ bkv, float* __restrict__ o) {
  int i = blockIdx.x * 256 + threadIdx.x;
  if (i < NQKV) o[i] = (i < DM) ? bq[i] : bkv[i - DM];
}

// ---------------- 256x256 8-phase bf16 GEMM (T2+T3+T4+T5) ----------------
// 512 thr = 8 waves (2M x 4N), BK=64, 2 K-tiles per iter, LDS 128 KB dbuf.
// Staging: global_load_lds w/ chunk-XOR pre-swizzled source; reads XOR back.
// vmcnt(6) only at phases 4/8. EPI=0: f32 C+bias. EPI=1: fused RoPE/scatter.

#define STA(buf, kt, q) gload_lds16(gA + (size_t)((q) * 32) * K + (kt), LW + (buf) * 65536 + ((q) * 32 + rowA) * 128)
#define STB(buf, kt, h) gload_lds16(gB + (size_t)((h) * 64) * K + (kt), LW + (buf) * 65536 + 32768 + ((h) * 64 + rowB) * 128)

#define RDB(buf) \
  _Pragma("unroll") for (int ni = 0; ni < 4; ++ni) { \
    int row_ = (EPI == 1) ? (wc * 16 + ni * 64 + ln) : (wc * 64 + ni * 16 + ln); \
    const char* p_ = (const char*)LW + (buf) * 65536 + 32768 + row_ * 128; \
    bfr[ni][0] = *(const short8*)(p_ + coff0); \
    bfr[ni][1] = *(const short8*)(p_ + coff1); }

#define RDA(buf, q) \
  _Pragma("unroll") for (int m2 = 0; m2 < 2; ++m2) { \
    int row_ = wr * 128 + ((q) * 2 + m2) * 16 + ln; \
    const char* p_ = (const char*)LW + (buf) * 65536 + row_ * 128; \
    af[m2][0] = *(const short8*)(p_ + coff0); \
    af[m2][1] = *(const short8*)(p_ + coff1); }

#define MFQ(q) \
  _Pragma("unroll") for (int m2 = 0; m2 < 2; ++m2) \
  _Pragma("unroll") for (int ni = 0; ni < 4; ++ni) { \
    acc[(q) * 2 + m2][ni] = __builtin_amdgcn_mfma_f32_16x16x32_bf16(af[m2][0], bfr[ni][0], acc[(q) * 2 + m2][ni], 0, 0, 0); \
    acc[(q) * 2 + m2][ni] = __builtin_amdgcn_mfma_f32_16x16x32_bf16(af[m2][1], bfr[ni][1], acc[(q) * 2 + m2][ni], 0, 0, 0); }

#define SYNC_IN() do { __builtin_amdgcn_sched_barrier(0); __builtin_amdgcn_s_barrier(); \
  asm volatile("s_waitcnt lgkmcnt(0)" ::: "memory"); __builtin_amdgcn_sched_barrier(0); \
  __builtin_amdgcn_s_setprio(1); } while (0)
#define SYNC_OUT() do { __builtin_amdgcn_s_setprio(0); __builtin_amdgcn_sched_barrier(0); \
  __builtin_amdgcn_s_barrier(); } while (0)
#define SYNC_OUT_VM() do { __builtin_amdgcn_s_setprio(0); \
  asm volatile("s_waitcnt vmcnt(6)" ::: "memory"); __builtin_amdgcn_sched_barrier(0); \
  __builtin_amdgcn_s_barrier(); } while (0)

template <int EPI>
__global__ __launch_bounds__(512, 2) void gemm8(
    const unsigned short* __restrict__ A, const unsigned short* __restrict__ Bt,
    const float* __restrict__ bias, const int* __restrict__ seq_pos,
    const float2* __restrict__ tbl,
    unsigned short* __restrict__ Qo, unsigned short* __restrict__ Ko,
    unsigned short* __restrict__ Vo, float* __restrict__ Cout,
    int nbx, int N, int K) {
  __shared__ __align__(16) unsigned short lds[2 * 2 * 16384];  // 128 KB: [buf][A/B][256*64]
  int tid = threadIdx.x, lane = tid & 63, w = tid >> 6;
  int wr = w >> 2, wc = w & 3;               // 2M x 4N wave grid
  int lg = lane >> 4, ln = lane & 15;

  // XCD-aware bijective swizzle (gridDim.x % 8 == 0)
  int bid = blockIdx.x;
  int cpx = gridDim.x >> 3;
  int swz = (bid & 7) * cpx + (bid >> 3);
  int by = swz / nbx, bx = swz - by * nbx;
  int m0 = by * 256, n0 = bx * 256;

  // staging: lane covers row (+lane>>3), source chunk (lane&7)^(lane>>3) [row-indep since bases %8==0]
  int soff = ((lane & 7) ^ (lane >> 3)) << 3;
  const unsigned short* gA = A + (size_t)(m0 + ((w & 3) << 3) + ((w >> 2) << 7) + (lane >> 3)) * K + soff;
  const unsigned short* gB = Bt + (size_t)(n0 + (w << 3) + (lane >> 3)) * K + soff;
  char* LW = (char*)lds;
  int rowA = ((w & 3) << 3) + ((w >> 2) << 7);   // wave-uniform A staging base row
  int rowB = (w << 3);
  // read-side swizzled chunk offsets (row&7 == ln&7 for all frag rows)
  int coff0 = ((lg)     ^ (ln & 7)) << 4;
  int coff1 = ((lg + 4) ^ (ln & 7)) << 4;

  f32x4 acc[8][4];
#pragma unroll
  for (int mi = 0; mi < 8; ++mi)
#pragma unroll
    for (int ni = 0; ni < 4; ++ni) acc[mi][ni] = (f32x4){0, 0, 0, 0};

  short8 bfr[4][2], af[2][2];

  // prologue: tile0 (8 issues), tile1 first 6 issues; vmcnt(6) -> tile0 landed
  STB(0, 0, 0); STB(0, 0, 1); STB(0, 0, 2); STB(0, 0, 3);
  STA(0, 0, 0); STA(0, 0, 1); STA(0, 0, 2); STA(0, 0, 3);
  STB(1, 64, 0); STB(1, 64, 1); STB(1, 64, 2); STB(1, 64, 3);
  STA(1, 64, 0); STA(1, 64, 1);
  asm volatile("s_waitcnt vmcnt(6)" ::: "memory");
  __builtin_amdgcn_sched_barrier(0);
  __builtin_amdgcn_s_barrier();

  for (int it = 0; it < (K >> 7); ++it) {
    int kt1  = it * 128 + 64;               // buf1's current tile (finish its A here)
    int ktn0 = (it * 128 + 128) & (K - 1);  // next buf0 tile
    int ktn1 = (it * 128 + 192) & (K - 1);  // next buf1 tile
    // phase 1: buf0 q0 (+ all B of buf0)
    RDB(0); RDA(0, 0);
    STA(1, kt1, 2); STA(1, kt1, 3);
    SYNC_IN(); MFQ(0); SYNC_OUT();
    // phase 2
    RDA(0, 1);
    STB(0, ktn0, 0); STB(0, ktn0, 1);
    SYNC_IN(); MFQ(1); SYNC_OUT();
    // phase 3
    RDA(0, 2);
    STB(0, ktn0, 2); STB(0, ktn0, 3);
    SYNC_IN(); MFQ(2); SYNC_OUT();
    // phase 4 (vmcnt(6): tile kt1 fully landed for phases 5-8)
    RDA(0, 3);
    STA(0, ktn0, 0); STA(0, ktn0, 1);
    SYNC_IN(); MFQ(3); SYNC_OUT_VM();
    // phase 5: buf1 q0 (+ all B of buf1)
    RDB(1); RDA(1, 0);
    STA(0, ktn0, 2); STA(0, ktn0, 3);
    SYNC_IN(); MFQ(0); SYNC_OUT();
    // phase 6
    RDA(1, 1);
    STB(1, ktn1, 0); STB(1, ktn1, 1);
    SYNC_IN(); MFQ(1); SYNC_OUT();
    // phase 7
    RDA(1, 2);
    STB(1, ktn1, 2); STB(1, ktn1, 3);
    SYNC_IN(); MFQ(2); SYNC_OUT();
    // phase 8 (vmcnt(6): tile ktn0 fully landed for next iter)
    RDA(1, 3);
    STA(1, ktn1, 0); STA(1, ktn1, 1);
    SYNC_IN(); MFQ(3); SYNC_OUT_VM();
  }
  asm volatile("s_waitcnt vmcnt(0)" ::: "memory");  // drain wrapped tail stages

  if constexpr (EPI == 0) {
    // plain f32 C + bias; col = n0 + wc*64 + ni*16 + ln
#pragma unroll
    for (int mi = 0; mi < 8; ++mi) {
      int row = m0 + wr * 128 + mi * 16 + lg * 4;
#pragma unroll
      for (int ni = 0; ni < 4; ++ni) {
        int col = n0 + wc * 64 + ni * 16 + ln;
        float bv = bias[col];
#pragma unroll
        for (int r = 0; r < 4; ++r)
          Cout[(size_t)(row + r) * N + col] = acc[mi][ni][r] + bv;
      }
    }
  } else {
    // col = n0 + wc*16 + ni*64 + ln  ->  RoPE pairs (d, d+64) are lane-local
    int d = wc * 16 + ln;
    float bv0 = bias[n0 + d],      bv1 = bias[n0 + d + 64];
    float bv2 = bias[n0 + d + 128], bv3 = bias[n0 + d + 192];
    int bI = m0 >> 11, s0 = m0 & (SEQ - 1);
    int nt = n0 >> 8;
    if (nt < 8) {
      // two Q heads: h0 = 2*nt (ni 0,1), h0+1 (ni 2,3)
      unsigned short* qp0 = Qo + (size_t)(bI * NH + nt * 2) * SEQ * HD;
      unsigned short* qp1 = qp0 + (size_t)SEQ * HD;
#pragma unroll
      for (int mi = 0; mi < 8; ++mi) {
        int sl = wr * 128 + mi * 16 + lg * 4;
#pragma unroll
        for (int r = 0; r < 4; ++r) {
          int s = s0 + sl + r;
          int pos = seq_pos[bI * SEQ + s];
          float2 cs = tbl[pos * 64 + d];
          float x1 = acc[mi][0][r] + bv0, x2 = acc[mi][1][r] + bv1;
          float y1 = acc[mi][2][r] + bv2, y2 = acc[mi][3][r] + bv3;
          unsigned short* q0 = qp0 + (size_t)s * HD;
          q0[d]      = f2bf((x1 * cs.x - x2 * cs.y) * QSC);
          q0[d + 64] = f2bf((x2 * cs.x + x1 * cs.y) * QSC);
          unsigned short* q1 = qp1 + (size_t)s * HD;
          q1[d]      = f2bf((y1 * cs.x - y2 * cs.y) * QSC);
          q1[d + 64] = f2bf((y2 * cs.x + y1 * cs.y) * QSC);
        }
      }
    } else {
      // kv head: ni 0,1 = K (RoPE), ni 2,3 = V (transpose to Vt[d][s])
      int kvh = nt - 8;
      unsigned short* kp = Ko + (size_t)(bI * NKVH + kvh) * SEQ * HD;
      unsigned short* vp = Vo + (size_t)(bI * NKVH + kvh) * HD * SEQ;
#pragma unroll
      for (int mi = 0; mi < 8; ++mi) {
        int sl = wr * 128 + mi * 16 + lg * 4;
        ushort4 v0q, v1q;
#pragma unroll
        for (int r = 0; r < 4; ++r) {
          int s = s0 + sl + r;
          int pos = seq_pos[bI * SEQ + s];
          float2 cs = tbl[pos * 64 + d];
          float x1 = acc[mi][0][r] + bv0, x2 = acc[mi][1][r] + bv1;
          unsigned short* krow = kp + (size_t)s * HD;
          krow[d]      = f2bf(x1 * cs.x - x2 * cs.y);
          krow[d + 64] = f2bf(x2 * cs.x + x1 * cs.y);
          ((unsigned short*)&v0q)[r] = f2bf(acc[mi][2][r] + bv2);
          ((unsigned short*)&v1q)[r] = f2bf(acc[mi][3][r] + bv3);
        }
        *(ushort4*)(vp + (size_t)d * SEQ + s0 + sl)        = v0q;
        *(ushort4*)(vp + (size_t)(d + 64) * SEQ + s0 + sl) = v1q;
      }
    }
  }
}

// ---------------- causal GQA flash attention v4 (unchanged from round 4) ----------------

__global__ __launch_bounds__(256) void flash_attn(const unsigned short* __restrict__ Q,
                                                  const unsigned short* __restrict__ Kr,
                                                  const unsigned short* __restrict__ Vt,
                                                  const int* __restrict__ seq_pos,
                                                  unsigned short* __restrict__ X) {
  __shared__ __align__(16) unsigned short lds_k[64 * 128];   // [kv][d], swizzle via source
  __shared__ __align__(16) unsigned short lds_v[128 * 64];   // [d][kv], swizzle via source
  __shared__ __align__(16) unsigned short lds_p[4][16 * 64]; // per-wave P swizzled
  int tid = threadIdx.x, lane = tid & 63, w = tid >> 6;
  int bh = blockIdx.y, b = bh >> 4, h = bh & 15, kvh = h >> 2;
  int lg = lane >> 4, ln = lane & 15;

  const unsigned short* kbase = Kr + ((size_t)(b * NKVH + kvh)) * SEQ * HD;
  const unsigned short* vbase = Vt + ((size_t)(b * NKVH + kvh)) * HD * SEQ;

  const unsigned short* gks[4]; unsigned short* lks[4];
  const unsigned short* gvs[4]; unsigned short* lvs[4];
#pragma unroll
  for (int i = 0; i < 4; i++) {
    int kr = w * 16 + i * 4 + (lane >> 4);
    int kc = (lane & 15) ^ (kr & 7);
    gks[i] = kbase + (size_t)kr * HD + kc * 8;
    lks[i] = lds_k + (w * 16 + i * 4) * 128;
    int vr = w * 32 + i * 8 + (lane >> 3);
    int vc = (lane & 7) ^ (vr & 7);
    gvs[i] = vbase + (size_t)vr * SEQ + vc * 8;
    lvs[i] = lds_v + (w * 32 + i * 8) * 64;
  }

  const short8 ones = {0x3F80, 0x3F80, 0x3F80, 0x3F80, 0x3F80, 0x3F80, 0x3F80, 0x3F80};

  for (int pass = 0; pass < 2; pass++) {
    int qtile = (pass == 0) ? (int)blockIdx.x : (SEQ / 64 - 1 - (int)blockIdx.x);
    int qblk = qtile * 64;
    int q0w = qblk + w * 16;

    int pmax = seq_pos[b * SEQ + qblk + lane];
    for (int o = 32; o; o >>= 1) { int t2 = __shfl_xor(pmax, o); pmax = pmax > t2 ? pmax : t2; }
    int ntiles = (pmax + KVB) >> 6;
    if (ntiles > SEQ / KVB) ntiles = SEQ / KVB;

    int pos_r[4];
    for (int r = 0; r < 4; r++) pos_r[r] = seq_pos[b * SEQ + q0w + lg * 4 + r];

    short8 qf[4];
    {
      const unsigned short* qp = Q + ((size_t)((b * NH + h) * SEQ + q0w + ln)) * HD;
      for (int c = 0; c < 4; c++) qf[c] = *reinterpret_cast<const short8*>(qp + c * 32 + lg * 8);
    }

    f32x4 acc[8];
    for (int dt = 0; dt < 8; dt++) acc[dt] = (f32x4){0, 0, 0, 0};
    f32x4 lacc = (f32x4){0, 0, 0, 0};
    float m_r[4] = {-1e30f, -1e30f, -1e30f, -1e30f};

    for (int t = 0; t < ntiles; t++) {
      int kv0 = t * KVB;
#pragma unroll
      for (int i = 0; i < 4; i++) {
        gload_lds16(gks[i] + (size_t)kv0 * HD, lks[i]);
        gload_lds16(gvs[i] + kv0, lvs[i]);
      }
      __syncthreads();

      f32x4 sa[4];
#pragma unroll
      for (int ct = 0; ct < 4; ct++) {
        sa[ct] = (f32x4){0, 0, 0, 0};
        int row = ct * 16 + ln;
        const char* kr0 = (const char*)lds_k + row * 256;
        int sw = (row & 7) << 4;
#pragma unroll
        for (int c = 0; c < 4; c++) {
          short8 kf = *reinterpret_cast<const short8*>(kr0 + ((c * 64 + lg * 16) ^ sw));
          sa[ct] = __builtin_amdgcn_mfma_f32_16x16x32_bf16(qf[c], kf, sa[ct], 0, 0, 0);
        }
      }

      float p[4][4], corr[4];
#pragma unroll
      for (int r = 0; r < 4; r++) {
        int kv = kv0 + ln;
        float v0 = (kv      <= pos_r[r]) ? sa[0][r] : -1e30f;
        float v1 = (kv + 16 <= pos_r[r]) ? sa[1][r] : -1e30f;
        float v2 = (kv + 32 <= pos_r[r]) ? sa[2][r] : -1e30f;
        float v3 = (kv + 48 <= pos_r[r]) ? sa[3][r] : -1e30f;
        float tmx = fmaxf(fmaxf(v0, v1), fmaxf(v2, v3));
        tmx = fmaxf(tmx, __shfl_xor(tmx, 1));
        tmx = fmaxf(tmx, __shfl_xor(tmx, 2));
        tmx = fmaxf(tmx, __shfl_xor(tmx, 4));
        tmx = fmaxf(tmx, __shfl_xor(tmx, 8));
        float nm = fmaxf(m_r[r], tmx);
        corr[r] = __expf(m_r[r] - nm);
        p[0][r] = __expf(v0 - nm); p[1][r] = __expf(v1 - nm);
        p[2][r] = __expf(v2 - nm); p[3][r] = __expf(v3 - nm);
        m_r[r] = nm;
      }

      {
        char* pw = (char*)lds_p[w];
#pragma unroll
        for (int r = 0; r < 4; r++) {
          int row = lg * 4 + r;
          int sw2 = (row & 7) << 4;
          char* pr = pw + row * 128;
#pragma unroll
          for (int ct = 0; ct < 4; ct++)
            *reinterpret_cast<unsigned short*>(pr + (((ct * 16 + ln) * 2) ^ sw2)) = f2bf(p[ct][r]);
        }
      }

#pragma unroll
      for (int dt = 0; dt < 8; dt++)
#pragma unroll
        for (int r = 0; r < 4; r++) acc[dt][r] *= corr[r];
#pragma unroll
      for (int r = 0; r < 4; r++) lacc[r] *= corr[r];

      asm volatile("s_waitcnt lgkmcnt(0)" ::: "memory");
      __builtin_amdgcn_sched_barrier(0);
      short8 pf[2];
      {
        const char* pr = (const char*)lds_p[w] + ln * 128;
        int sw2 = (ln & 7) << 4;
        pf[0] = *reinterpret_cast<const short8*>(pr + ((lg * 16) ^ sw2));
        pf[1] = *reinterpret_cast<const short8*>(pr + ((64 + lg * 16) ^ sw2));
      }

#pragma unroll
      for (int dt = 0; dt < 8; dt++) {
        int row = dt * 16 + ln;
        const char* vr0 = (const char*)lds_v + row * 128;
        int sw3 = (row & 7) << 4;
        short8 vf0 = *reinterpret_cast<const short8*>(vr0 + ((lg * 16) ^ sw3));
        short8 vf1 = *reinterpret_cast<const short8*>(vr0 + ((64 + lg * 16) ^ sw3));
        acc[dt] = __builtin_amdgcn_mfma_f32_16x16x32_bf16(pf[0], vf0, acc[dt], 0, 0, 0);
        acc[dt] = __builtin_amdgcn_mfma_f32_16x16x32_bf16(pf[1], vf1, acc[dt], 0, 0, 0);
      }
      lacc = __builtin_amdgcn_mfma_f32_16x16x32_bf16(pf[0], ones, lacc, 0, 0, 0);
      lacc = __builtin_amdgcn_mfma_f32_16x16x32_bf16(pf[1], ones, lacc, 0, 0, 0);
      __syncthreads();
    }

    for (int r = 0; r < 4; r++) {
      float inv = lacc[r] > 0.0f ? 1.0f / lacc[r] : 0.0f;
      int qrow = q0w + lg * 4 + r;
      unsigned short* xp = X + ((size_t)(b * SEQ + qrow)) * DM + h * HD;
      for (int dt = 0; dt < 8; dt++) xp[dt * 16 + ln] = f2bf(acc[dt][r] * inv);
    }
  }
}

// ---------------- launch ----------------

extern "C" void kernel_launch(void* const* d_in, const int* in_sizes, int n_in,
                              void* d_out, int out_size, void* d_ws, size_t ws_size,
                              hipStream_t stream) {
  const float* inputs  = (const float*)d_in[0];
  const int*   seq_pos = (const int*)d_in[1];
  const float* wq  = (const float*)d_in[2];
  const float* bq  = (const float*)d_in[3];
  const float* wkv = (const float*)d_in[4];
  const float* bkv = (const float*)d_in[5];
  const float* wo  = (const float*)d_in[6];
  const float* bo  = (const float*)d_in[7];
  float* out = (float*)d_out;

  char* ws = (char*)d_ws;
  unsigned short* Abf     = (unsigned short*)(ws + 0);          // 16.78 MB
  unsigned short* WqkvT   = (unsigned short*)(ws + 16777216);   // 12.58 MB
  unsigned short* WoT     = (unsigned short*)(ws + 29360128);   // 8.39 MB
  float*          biasqkv = (float*)(ws + 37748736);            // 12 KB
  float2*         tbl     = (float2*)(ws + 37761024);           // 1 MB
  unsigned short* Qr      = (unsigned short*)(ws + 38809600);   // 16.78 MB
  unsigned short* Kr      = (unsigned short*)(ws + 55586816);   // 4.19 MB
  unsigned short* Vt      = (unsigned short*)(ws + 59781120);   // 4.19 MB
  unsigned short* Xb      = (unsigned short*)(ws + 63975424);   // 16.78 MB (end ~80.8 MB)

  build_trig<<<512, 256, 0, stream>>>(tbl);
  f32_to_bf16_vec<<<8192, 256, 0, stream>>>(inputs, Abf, (NB * SEQ * DM) / 4);
  transpose_all<<<dim3(160, 64), dim3(32, 8), 0, stream>>>(wq, wkv, wo, WqkvT, WoT);
  bias_concat<<<12, 256, 0, stream>>>(bq, bkv, biasqkv);

  // QKV GEMM: M=4096, N=3072, K=2048; fused RoPE/scatter epilogue
  gemm8<1><<<(MROWS / 256) * (NQKV / 256), 512, 0, stream>>>(
      Abf, WqkvT, biasqkv, seq_pos, tbl, Qr, Kr, Vt, nullptr, NQKV / 256, NQKV, DM);

  flash_attn<<<dim3(SEQ / 128, NB * NH), 256, 0, stream>>>(Qr, Kr, Vt, seq_pos, Xb);

  // out-proj GEMM: M=4096, N=2048, K=2048, f32 out + bias
  gemm8<0><<<(MROWS / 256) * (DM / 256), 512, 0, stream>>>(
      Xb, WoT, bo, nullptr, nullptr, nullptr, nullptr, nullptr, out, DM / 256, DM, DM);
}

// Round 6
// 308.775 us; speedup vs baseline: 1.4856x; 1.0190x over previous
//
#include <hip/hip_runtime.h>
#include <hip/hip_bf16.h>

// Problem dims
#define DM    2048
#define SEQ   2048
#define NB    2
#define NH    16
#define NKVH  4
#define HD    128
#define NQKV  3072   // 2048 q cols + 1024 kv cols
#define MROWS 4096   // B*S
#define KVB   64
#define QSC   0.08838834764831845f

using f32x4  = __attribute__((ext_vector_type(4))) float;
using f32x16 = __attribute__((ext_vector_type(16))) float;
using short8 = __attribute__((ext_vector_type(8))) short;
using ushort8 = __attribute__((ext_vector_type(8))) unsigned short;
using uint2v = __attribute__((ext_vector_type(2))) unsigned int;

static __device__ __forceinline__ unsigned short f2bf(float f) {
  __hip_bfloat16 h = __float2bfloat16(f);
  return *reinterpret_cast<unsigned short*>(&h);
}
static __device__ __forceinline__ float bf2f(unsigned short u) {
  union { unsigned int i; float f; } v; v.i = ((unsigned int)u) << 16; return v.f;
}
static __device__ __forceinline__ unsigned cvtpk_bf16(float lo, float hi) {
  unsigned r;
  asm("v_cvt_pk_bf16_f32 %0, %1, %2" : "=v"(r) : "v"(lo), "v"(hi));
  return r;
}

// async global->LDS, 16B per lane; LDS dest is wave-uniform base + lane*16
typedef __attribute__((address_space(1))) const unsigned char as1_c;
typedef __attribute__((address_space(3))) unsigned char as3_c;
static __device__ __forceinline__ void gload_lds16(const void* g, void* l) {
  __builtin_amdgcn_global_load_lds((as1_c*)g, (as3_c*)l, 16, 0, 0);
}

// ---------------- trig table ----------------

__global__ void build_trig(float2* __restrict__ tbl) {
  int i = blockIdx.x * 256 + threadIdx.x;   // 2048*64
  int p = i >> 6, d = i & 63;
  float inv_ts = powf(10000.0f, -(float)d * (1.0f / 64.0f));
  float ang = (float)p * inv_ts;
  float sn, cs;
  sincosf(ang, &sn, &cs);
  tbl[i] = make_float2(cs, sn);
}

// ---------------- elementwise converts / transposes ----------------

__global__ void f32_to_bf16_vec(const float* __restrict__ src, unsigned short* __restrict__ dst, int n4) {
  int i = blockIdx.x * blockDim.x + threadIdx.x;
  if (i < n4) {
    float4 v = reinterpret_cast<const float4*>(src)[i];
    ushort4 o;
    o.x = f2bf(v.x); o.y = f2bf(v.y); o.z = f2bf(v.z); o.w = f2bf(v.w);
    reinterpret_cast<ushort4*>(dst)[i] = o;
  }
}

__global__ void transpose_all(const float* __restrict__ wq, const float* __restrict__ wkv,
                              const float* __restrict__ wo,
                              unsigned short* __restrict__ WqkvT, unsigned short* __restrict__ WoT) {
  int bx = blockIdx.x;
  const float* src; unsigned short* dst; int N;
  if (bx < 64)       { src = wq;  dst = WqkvT;                         N = 2048; }
  else if (bx < 96)  { src = wkv; dst = WqkvT + (size_t)2048 * DM;     N = 1024; bx -= 64; }
  else               { src = wo;  dst = WoT;                           N = 2048; bx -= 96; }
  __shared__ float t[32][33];
  int n0 = bx * 32, k0 = blockIdx.y * 32;
  int tx = threadIdx.x, ty = threadIdx.y;  // 32 x 8
  for (int j = 0; j < 4; j++)
    t[ty + j * 8][tx] = src[(size_t)(k0 + ty + j * 8) * N + n0 + tx];
  __syncthreads();
  for (int j = 0; j < 4; j++)
    dst[(size_t)(n0 + ty + j * 8) * DM + k0 + tx] = f2bf(t[tx][ty + j * 8]);
}

__global__ void bias_concat(const float* __restrict__ bq, const float* __restrict__ bkv, float* __restrict__ o) {
  int i = blockIdx.x * 256 + threadIdx.x;
  if (i < NQKV) o[i] = (i < DM) ? bq[i] : bkv[i - DM];
}

// ---------------- 256x256 8-phase bf16 GEMM (T2+T3+T4+T5) ----------------

#define STA(buf, kt, q) gload_lds16(gA + (size_t)((q) * 32) * K + (kt), LW + (buf) * 65536 + ((q) * 32 + rowA) * 128)
#define STB(buf, kt, h) gload_lds16(gB + (size_t)((h) * 64) * K + (kt), LW + (buf) * 65536 + 32768 + ((h) * 64 + rowB) * 128)

#define RDB(buf) \
  _Pragma("unroll") for (int ni = 0; ni < 4; ++ni) { \
    int row_ = (EPI == 1) ? (wc * 16 + ni * 64 + ln) : (wc * 64 + ni * 16 + ln); \
    const char* p_ = (const char*)LW + (buf) * 65536 + 32768 + row_ * 128; \
    bfr[ni][0] = *(const short8*)(p_ + coff0); \
    bfr[ni][1] = *(const short8*)(p_ + coff1); }

#define RDA(buf, q) \
  _Pragma("unroll") for (int m2 = 0; m2 < 2; ++m2) { \
    int row_ = wr * 128 + ((q) * 2 + m2) * 16 + ln; \
    const char* p_ = (const char*)LW + (buf) * 65536 + row_ * 128; \
    af[m2][0] = *(const short8*)(p_ + coff0); \
    af[m2][1] = *(const short8*)(p_ + coff1); }

#define MFQ(q) \
  _Pragma("unroll") for (int m2 = 0; m2 < 2; ++m2) \
  _Pragma("unroll") for (int ni = 0; ni < 4; ++ni) { \
    acc[(q) * 2 + m2][ni] = __builtin_amdgcn_mfma_f32_16x16x32_bf16(af[m2][0], bfr[ni][0], acc[(q) * 2 + m2][ni], 0, 0, 0); \
    acc[(q) * 2 + m2][ni] = __builtin_amdgcn_mfma_f32_16x16x32_bf16(af[m2][1], bfr[ni][1], acc[(q) * 2 + m2][ni], 0, 0, 0); }

#define SYNC_IN() do { __builtin_amdgcn_sched_barrier(0); __builtin_amdgcn_s_barrier(); \
  asm volatile("s_waitcnt lgkmcnt(0)" ::: "memory"); __builtin_amdgcn_sched_barrier(0); \
  __builtin_amdgcn_s_setprio(1); } while (0)
#define SYNC_OUT() do { __builtin_amdgcn_s_setprio(0); __builtin_amdgcn_sched_barrier(0); \
  __builtin_amdgcn_s_barrier(); } while (0)
#define SYNC_OUT_VM() do { __builtin_amdgcn_s_setprio(0); \
  asm volatile("s_waitcnt vmcnt(6)" ::: "memory"); __builtin_amdgcn_sched_barrier(0); \
  __builtin_amdgcn_s_barrier(); } while (0)

template <int EPI>
__global__ __launch_bounds__(512, 2) void gemm8(
    const unsigned short* __restrict__ A, const unsigned short* __restrict__ Bt,
    const float* __restrict__ bias, const int* __restrict__ seq_pos,
    const float2* __restrict__ tbl,
    unsigned short* __restrict__ Qo, unsigned short* __restrict__ Ko,
    unsigned short* __restrict__ Vo, float* __restrict__ Cout,
    int nbx, int N, int K) {
  __shared__ __align__(16) unsigned short lds[2 * 2 * 16384];  // 128 KB
  int tid = threadIdx.x, lane = tid & 63, w = tid >> 6;
  int wr = w >> 2, wc = w & 3;
  int lg = lane >> 4, ln = lane & 15;

  int bid = blockIdx.x;
  int cpx = gridDim.x >> 3;
  int swz = (bid & 7) * cpx + (bid >> 3);
  int by = swz / nbx, bx = swz - by * nbx;
  int m0 = by * 256, n0 = bx * 256;

  int soff = ((lane & 7) ^ (lane >> 3)) << 3;
  const unsigned short* gA = A + (size_t)(m0 + ((w & 3) << 3) + ((w >> 2) << 7) + (lane >> 3)) * K + soff;
  const unsigned short* gB = Bt + (size_t)(n0 + (w << 3) + (lane >> 3)) * K + soff;
  char* LW = (char*)lds;
  int rowA = ((w & 3) << 3) + ((w >> 2) << 7);
  int rowB = (w << 3);
  int coff0 = ((lg)     ^ (ln & 7)) << 4;
  int coff1 = ((lg + 4) ^ (ln & 7)) << 4;

  f32x4 acc[8][4];
#pragma unroll
  for (int mi = 0; mi < 8; ++mi)
#pragma unroll
    for (int ni = 0; ni < 4; ++ni) acc[mi][ni] = (f32x4){0, 0, 0, 0};

  short8 bfr[4][2], af[2][2];

  STB(0, 0, 0); STB(0, 0, 1); STB(0, 0, 2); STB(0, 0, 3);
  STA(0, 0, 0); STA(0, 0, 1); STA(0, 0, 2); STA(0, 0, 3);
  STB(1, 64, 0); STB(1, 64, 1); STB(1, 64, 2); STB(1, 64, 3);
  STA(1, 64, 0); STA(1, 64, 1);
  asm volatile("s_waitcnt vmcnt(6)" ::: "memory");
  __builtin_amdgcn_sched_barrier(0);
  __builtin_amdgcn_s_barrier();

  for (int it = 0; it < (K >> 7); ++it) {
    int kt1  = it * 128 + 64;
    int ktn0 = (it * 128 + 128) & (K - 1);
    int ktn1 = (it * 128 + 192) & (K - 1);
    RDB(0); RDA(0, 0);
    STA(1, kt1, 2); STA(1, kt1, 3);
    SYNC_IN(); MFQ(0); SYNC_OUT();
    RDA(0, 1);
    STB(0, ktn0, 0); STB(0, ktn0, 1);
    SYNC_IN(); MFQ(1); SYNC_OUT();
    RDA(0, 2);
    STB(0, ktn0, 2); STB(0, ktn0, 3);
    SYNC_IN(); MFQ(2); SYNC_OUT();
    RDA(0, 3);
    STA(0, ktn0, 0); STA(0, ktn0, 1);
    SYNC_IN(); MFQ(3); SYNC_OUT_VM();
    RDB(1); RDA(1, 0);
    STA(0, ktn0, 2); STA(0, ktn0, 3);
    SYNC_IN(); MFQ(0); SYNC_OUT();
    RDA(1, 1);
    STB(1, ktn1, 0); STB(1, ktn1, 1);
    SYNC_IN(); MFQ(1); SYNC_OUT();
    RDA(1, 2);
    STB(1, ktn1, 2); STB(1, ktn1, 3);
    SYNC_IN(); MFQ(2); SYNC_OUT();
    RDA(1, 3);
    STA(1, ktn1, 0); STA(1, ktn1, 1);
    SYNC_IN(); MFQ(3); SYNC_OUT_VM();
  }
  asm volatile("s_waitcnt vmcnt(0)" ::: "memory");

  if constexpr (EPI == 0) {
#pragma unroll
    for (int mi = 0; mi < 8; ++mi) {
      int row = m0 + wr * 128 + mi * 16 + lg * 4;
#pragma unroll
      for (int ni = 0; ni < 4; ++ni) {
        int col = n0 + wc * 64 + ni * 16 + ln;
        float bv = bias[col];
#pragma unroll
        for (int r = 0; r < 4; ++r)
          Cout[(size_t)(row + r) * N + col] = acc[mi][ni][r] + bv;
      }
    }
  } else {
    int d = wc * 16 + ln;
    float bv0 = bias[n0 + d],      bv1 = bias[n0 + d + 64];
    float bv2 = bias[n0 + d + 128], bv3 = bias[n0 + d + 192];
    int bI = m0 >> 11, s0 = m0 & (SEQ - 1);
    int nt = n0 >> 8;
    if (nt < 8) {
      unsigned short* qp0 = Qo + (size_t)(bI * NH + nt * 2) * SEQ * HD;
      unsigned short* qp1 = qp0 + (size_t)SEQ * HD;
#pragma unroll
      for (int mi = 0; mi < 8; ++mi) {
        int sl = wr * 128 + mi * 16 + lg * 4;
#pragma unroll
        for (int r = 0; r < 4; ++r) {
          int s = s0 + sl + r;
          int pos = seq_pos[bI * SEQ + s];
          float2 cs = tbl[pos * 64 + d];
          float x1 = acc[mi][0][r] + bv0, x2 = acc[mi][1][r] + bv1;
          float y1 = acc[mi][2][r] + bv2, y2 = acc[mi][3][r] + bv3;
          unsigned short* q0 = qp0 + (size_t)s * HD;
          q0[d]      = f2bf((x1 * cs.x - x2 * cs.y) * QSC);
          q0[d + 64] = f2bf((x2 * cs.x + x1 * cs.y) * QSC);
          unsigned short* q1 = qp1 + (size_t)s * HD;
          q1[d]      = f2bf((y1 * cs.x - y2 * cs.y) * QSC);
          q1[d + 64] = f2bf((y2 * cs.x + y1 * cs.y) * QSC);
        }
      }
    } else {
      int kvh = nt - 8;
      unsigned short* kp = Ko + (size_t)(bI * NKVH + kvh) * SEQ * HD;
      unsigned short* vp = Vo + (size_t)(bI * NKVH + kvh) * HD * SEQ;
#pragma unroll
      for (int mi = 0; mi < 8; ++mi) {
        int sl = wr * 128 + mi * 16 + lg * 4;
        ushort4 v0q, v1q;
#pragma unroll
        for (int r = 0; r < 4; ++r) {
          int s = s0 + sl + r;
          int pos = seq_pos[bI * SEQ + s];
          float2 cs = tbl[pos * 64 + d];
          float x1 = acc[mi][0][r] + bv0, x2 = acc[mi][1][r] + bv1;
          unsigned short* krow = kp + (size_t)s * HD;
          krow[d]      = f2bf(x1 * cs.x - x2 * cs.y);
          krow[d + 64] = f2bf(x2 * cs.x + x1 * cs.y);
          ((unsigned short*)&v0q)[r] = f2bf(acc[mi][2][r] + bv2);
          ((unsigned short*)&v1q)[r] = f2bf(acc[mi][3][r] + bv3);
        }
        *(ushort4*)(vp + (size_t)d * SEQ + s0 + sl)        = v0q;
        *(ushort4*)(vp + (size_t)(d + 64) * SEQ + s0 + sl) = v1q;
      }
    }
  }
}

// ---------------- causal GQA flash attention v5: swapped-QK^T 32x32 (T12) ----------------
// grid (16, 32): block = 128 q-rows (4 waves x 32), qtile = 15-bx (LPT order).
// Per 64-kv tile: S^T = mfma32x32x16(K,Q) -> lane owns one q-row's P in regs;
// lane-local softmax trees + 1 shfl_xor(32); P->B-frag via cvt_pk+permlane32_swap;
// O^T = mfma(V^T, P^T). T13 defer-max; T5 setprio; gload_lds staging (pre-swizzled src).

__global__ __launch_bounds__(256, 2) void flash_attn(const unsigned short* __restrict__ Q,
                                                     const unsigned short* __restrict__ Kr,
                                                     const unsigned short* __restrict__ Vt,
                                                     const int* __restrict__ seq_pos,
                                                     unsigned short* __restrict__ X) {
  __shared__ __align__(16) unsigned short lds_k[64 * 128];   // [kv][d], chunk-swizzled via source
  __shared__ __align__(16) unsigned short lds_v[128 * 64];   // [d][kv], chunk-swizzled via source
  int tid = threadIdx.x, lane = tid & 63, w = tid >> 6;
  int hi = lane >> 5, q5 = lane & 31;
  int bh = blockIdx.y, b = bh >> 4, h = bh & 15, kvhh = h >> 2;
  int qtile = 15 - (int)blockIdx.x;
  int qbase = qtile * 128;
  int q_global = qbase + w * 32 + q5;

  const unsigned short* kbase = Kr + ((size_t)(b * NKVH + kvhh)) * SEQ * HD;
  const unsigned short* vbase = Vt + ((size_t)(b * NKVH + kvhh)) * HD * SEQ;

  // staging (identical to v4): linear LDS dest, XOR-swizzled global source chunk
  const unsigned short* gks[4]; unsigned short* lks[4];
  const unsigned short* gvs[4]; unsigned short* lvs[4];
#pragma unroll
  for (int i = 0; i < 4; i++) {
    int kr = w * 16 + i * 4 + (lane >> 4);
    int kc = (lane & 15) ^ (kr & 7);
    gks[i] = kbase + (size_t)kr * HD + kc * 8;
    lks[i] = lds_k + (w * 16 + i * 4) * 128;
    int vr = w * 32 + i * 8 + (lane >> 3);
    int vc = (lane & 7) ^ (vr & 7);
    gvs[i] = vbase + (size_t)vr * SEQ + vc * 8;
    lvs[i] = lds_v + (w * 32 + i * 8) * 64;
  }

  // block-uniform tile count (each wave reduces over all 128 rows)
  int pm = max(seq_pos[b * SEQ + qbase + lane], seq_pos[b * SEQ + qbase + 64 + lane]);
#pragma unroll
  for (int o = 32; o; o >>= 1) { int t2 = __shfl_xor(pm, o); pm = pm > t2 ? pm : t2; }
  int ntiles = (pm + KVB) >> 6;
  if (ntiles > SEQ / KVB) ntiles = SEQ / KVB;

  int pos_q = seq_pos[b * SEQ + q_global];
  int wmin = pos_q;
#pragma unroll
  for (int o = 32; o; o >>= 1) { int t2 = __shfl_xor(wmin, o); wmin = wmin < t2 ? wmin : t2; }

  // Q fragments: lane holds Q[q_global][c*16 + hi*8 + j], j=0..7 (B-operand layout)
  short8 qf[8];
  {
    const unsigned short* qp = Q + ((size_t)((b * NH + h) * SEQ + q_global)) * HD + hi * 8;
#pragma unroll
    for (int c = 0; c < 8; c++) qf[c] = *reinterpret_cast<const short8*>(qp + c * 16);
  }

  f32x16 acc[4];
#pragma unroll
  for (int db = 0; db < 4; db++)
#pragma unroll
    for (int r = 0; r < 16; ++r) acc[db][r] = 0.0f;
  float m_q = -1e30f, l_q = 0.0f;

  const char* kp0 = (const char*)lds_k + q5 * 256;   // K row q5 (subtile 0)
  const char* kp1 = kp0 + 32 * 256;                  // K row 32+q5
  int swk = (q5 & 7) << 4;

  for (int t = 0; t < ntiles; t++) {
    int kv0 = t * KVB;
#pragma unroll
    for (int i = 0; i < 4; i++) {
      gload_lds16(gks[i] + (size_t)kv0 * HD, lks[i]);
      gload_lds16(gvs[i] + kv0, lvs[i]);
    }
    __syncthreads();

    // QK^T: S^T[kv][q], two 32-kv subtiles, K=128 contraction = 8 mfma each
    f32x16 st0, st1;
#pragma unroll
    for (int r = 0; r < 16; ++r) { st0[r] = 0.0f; st1[r] = 0.0f; }
    __builtin_amdgcn_s_setprio(1);
#pragma unroll
    for (int c = 0; c < 8; c++) {
      short8 kf0 = *reinterpret_cast<const short8*>(kp0 + ((c * 32 + hi * 16) ^ swk));
      short8 kf1 = *reinterpret_cast<const short8*>(kp1 + ((c * 32 + hi * 16) ^ swk));
      st0 = __builtin_amdgcn_mfma_f32_32x32x16_bf16(kf0, qf[c], st0, 0, 0, 0);
      st1 = __builtin_amdgcn_mfma_f32_32x32x16_bf16(kf1, qf[c], st1, 0, 0, 0);
    }
    __builtin_amdgcn_s_setprio(0);

    // causal mask only on boundary tiles (wave-uniform branch)
    if (kv0 + 63 > wmin) {
      int kvb = kv0 + 4 * hi;
#pragma unroll
      for (int r = 0; r < 16; ++r) {
        int kg = kvb + (r & 3) + 8 * (r >> 2);
        if (kg > pos_q)      st0[r] = -1e30f;
        if (kg + 32 > pos_q) st1[r] = -1e30f;
      }
    }

    // row max: lane-local tree + one cross-half exchange
    float tm[16];
#pragma unroll
    for (int r = 0; r < 16; ++r) tm[r] = fmaxf(st0[r], st1[r]);
#pragma unroll
    for (int s = 8; s; s >>= 1)
#pragma unroll
      for (int r = 0; r < s; ++r) tm[r] = fmaxf(tm[r], tm[r + s]);
    float mx = fmaxf(tm[0], __shfl_xor(tm[0], 32));

    // T13 defer-max rescale
    bool skip = (mx <= m_q + 8.0f) && (m_q > -1e29f);
    if (!__all((int)skip)) {
      float nm = fmaxf(m_q, mx);
      float corr = __expf(m_q - nm);
      m_q = nm; l_q *= corr;
#pragma unroll
      for (int db = 0; db < 4; db++)
#pragma unroll
        for (int r = 0; r < 16; ++r) acc[db][r] *= corr;
    }

    // exp + row sum (lane-local tree + one exchange)
    float sm[16];
#pragma unroll
    for (int r = 0; r < 16; ++r) {
      st0[r] = __expf(st0[r] - m_q);
      st1[r] = __expf(st1[r] - m_q);
      sm[r] = st0[r] + st1[r];
    }
#pragma unroll
    for (int s = 8; s; s >>= 1)
#pragma unroll
      for (int r = 0; r < s; ++r) sm[r] += sm[r + s];
    l_q += sm[0] + __shfl_xor(sm[0], 32);

    // P -> bf16 B-fragments: cvt_pk pairs + permlane32_swap (T12)
    short8 pb[4];
#define MKFRAG(STV, B, OUT) { \
    unsigned a_ = cvtpk_bf16(STV[(B) + 0], STV[(B) + 1]); \
    unsigned b_ = cvtpk_bf16(STV[(B) + 2], STV[(B) + 3]); \
    unsigned c_ = cvtpk_bf16(STV[(B) + 4], STV[(B) + 5]); \
    unsigned d_ = cvtpk_bf16(STV[(B) + 6], STV[(B) + 7]); \
    uint2v r1_ = __builtin_amdgcn_permlane32_swap(a_, c_, false, false); \
    uint2v r2_ = __builtin_amdgcn_permlane32_swap(b_, d_, false, false); \
    union { unsigned u[4]; short8 s; } f_; \
    f_.u[0] = r1_[0]; f_.u[1] = r2_[0]; f_.u[2] = r1_[1]; f_.u[3] = r2_[1]; \
    OUT = f_.s; }
    MKFRAG(st0, 0, pb[0]);
    MKFRAG(st0, 8, pb[1]);
    MKFRAG(st1, 0, pb[2]);
    MKFRAG(st1, 8, pb[3]);
#undef MKFRAG

    // PV: O^T[d][q] += V^T[d][kv] * P^T[kv][q]
    __builtin_amdgcn_s_setprio(1);
#pragma unroll
    for (int db = 0; db < 4; db++) {
      const char* vr0 = (const char*)lds_v + (db * 32 + q5) * 128;
#pragma unroll
      for (int tt = 0; tt < 4; tt++) {
        short8 vf = *reinterpret_cast<const short8*>(vr0 + ((tt * 32 + hi * 16) ^ swk));
        acc[db] = __builtin_amdgcn_mfma_f32_32x32x16_bf16(vf, pb[tt], acc[db], 0, 0, 0);
      }
    }
    __builtin_amdgcn_s_setprio(0);
    __syncthreads();
  }

  // epilogue: O[q][d] = O^T[d][q]/l, d = db*32 + 4*hi + 8*rq + {0..3}
  float inv = l_q > 0.0f ? 1.0f / l_q : 0.0f;
  unsigned short* xp = X + ((size_t)(b * SEQ + q_global)) * DM + h * HD;
#pragma unroll
  for (int db = 0; db < 4; db++)
#pragma unroll
    for (int rq = 0; rq < 4; rq++) {
      int d = db * 32 + 4 * hi + 8 * rq;
      ushort4 o;
      unsigned short* op = (unsigned short*)&o;
#pragma unroll
      for (int j = 0; j < 4; j++) op[j] = f2bf(acc[db][rq * 4 + j] * inv);
      *(ushort4*)(xp + d) = o;
    }
}

// ---------------- launch ----------------

extern "C" void kernel_launch(void* const* d_in, const int* in_sizes, int n_in,
                              void* d_out, int out_size, void* d_ws, size_t ws_size,
                              hipStream_t stream) {
  const float* inputs  = (const float*)d_in[0];
  const int*   seq_pos = (const int*)d_in[1];
  const float* wq  = (const float*)d_in[2];
  const float* bq  = (const float*)d_in[3];
  const float* wkv = (const float*)d_in[4];
  const float* bkv = (const float*)d_in[5];
  const float* wo  = (const float*)d_in[6];
  const float* bo  = (const float*)d_in[7];
  float* out = (float*)d_out;

  char* ws = (char*)d_ws;
  unsigned short* Abf     = (unsigned short*)(ws + 0);          // 16.78 MB
  unsigned short* WqkvT   = (unsigned short*)(ws + 16777216);   // 12.58 MB
  unsigned short* WoT     = (unsigned short*)(ws + 29360128);   // 8.39 MB
  float*          biasqkv = (float*)(ws + 37748736);            // 12 KB
  float2*         tbl     = (float2*)(ws + 37761024);           // 1 MB
  unsigned short* Qr      = (unsigned short*)(ws + 38809600);   // 16.78 MB
  unsigned short* Kr      = (unsigned short*)(ws + 55586816);   // 4.19 MB
  unsigned short* Vt      = (unsigned short*)(ws + 59781120);   // 4.19 MB
  unsigned short* Xb      = (unsigned short*)(ws + 63975424);   // 16.78 MB (end ~80.8 MB)

  build_trig<<<512, 256, 0, stream>>>(tbl);
  f32_to_bf16_vec<<<8192, 256, 0, stream>>>(inputs, Abf, (NB * SEQ * DM) / 4);
  transpose_all<<<dim3(160, 64), dim3(32, 8), 0, stream>>>(wq, wkv, wo, WqkvT, WoT);
  bias_concat<<<12, 256, 0, stream>>>(bq, bkv, biasqkv);

  gemm8<1><<<(MROWS / 256) * (NQKV / 256), 512, 0, stream>>>(
      Abf, WqkvT, biasqkv, seq_pos, tbl, Qr, Kr, Vt, nullptr, NQKV / 256, NQKV, DM);

  flash_attn<<<dim3(16, NB * NH), 256, 0, stream>>>(Qr, Kr, Vt, seq_pos, Xb);

  gemm8<0><<<(MROWS / 256) * (DM / 256), 512, 0, stream>>>(
      Xb, WoT, bo, nullptr, nullptr, nullptr, nullptr, nullptr, out, DM / 256, DM, DM);
}

// Round 7
// 293.548 us; speedup vs baseline: 1.5626x; 1.0519x over previous
//
#include <hip/hip_runtime.h>
#include <hip/hip_bf16.h>

// Problem dims
#define DM    2048
#define SEQ   2048
#define NB    2
#define NH    16
#define NKVH  4
#define HD    128
#define NQKV  3072   // 2048 q cols + 1024 kv cols
#define MROWS 4096   // B*S
#define KVB   64
#define QSC   0.08838834764831845f

using f32x4  = __attribute__((ext_vector_type(4))) float;
using f32x16 = __attribute__((ext_vector_type(16))) float;
using short8 = __attribute__((ext_vector_type(8))) short;
using ushort8 = __attribute__((ext_vector_type(8))) unsigned short;
using uint2v = __attribute__((ext_vector_type(2))) unsigned int;

static __device__ __forceinline__ unsigned short f2bf(float f) {
  __hip_bfloat16 h = __float2bfloat16(f);
  return *reinterpret_cast<unsigned short*>(&h);
}
static __device__ __forceinline__ unsigned cvtpk_bf16(float lo, float hi) {
  unsigned r;
  asm("v_cvt_pk_bf16_f32 %0, %1, %2" : "=v"(r) : "v"(lo), "v"(hi));
  return r;
}

// async global->LDS, 16B per lane; LDS dest is wave-uniform base + lane*16
typedef __attribute__((address_space(1))) const unsigned char as1_c;
typedef __attribute__((address_space(3))) unsigned char as3_c;
static __device__ __forceinline__ void gload_lds16(const void* g, void* l) {
  __builtin_amdgcn_global_load_lds((as1_c*)g, (as3_c*)l, 16, 0, 0);
}

// ---------------- fused preamble: bf16-convert, weight transposes, trig table, bias ----------------
// blocks [0,8192): inputs f32->bf16 (float4/thread)
// blocks [8192,18432): 32x32 transpose tiles of wq/wkv/wo -> bf16 [N][K]
// blocks [18432,18944): trig table
// blocks [18944,18956): bias concat

__global__ __launch_bounds__(256) void preamble(
    const float* __restrict__ inputs, const float* __restrict__ wq,
    const float* __restrict__ wkv, const float* __restrict__ wo,
    const float* __restrict__ bq, const float* __restrict__ bkv,
    unsigned short* __restrict__ Abf, unsigned short* __restrict__ WqkvT,
    unsigned short* __restrict__ WoT, float* __restrict__ biasqkv,
    float2* __restrict__ tbl) {
  int blk = blockIdx.x, tid = threadIdx.x;
  if (blk < 8192) {
    int i = blk * 256 + tid;
    float4 v = reinterpret_cast<const float4*>(inputs)[i];
    ushort4 o;
    o.x = f2bf(v.x); o.y = f2bf(v.y); o.z = f2bf(v.z); o.w = f2bf(v.w);
    reinterpret_cast<ushort4*>(Abf)[i] = o;
  } else if (blk < 18432) {
    int rb = blk - 8192;
    int bxx = rb % 160, byy = rb / 160;
    const float* src; unsigned short* dst; int N;
    if (bxx < 64)      { src = wq;  dst = WqkvT;                     N = 2048; }
    else if (bxx < 96) { src = wkv; dst = WqkvT + (size_t)2048 * DM; N = 1024; bxx -= 64; }
    else               { src = wo;  dst = WoT;                       N = 2048; bxx -= 96; }
    __shared__ float t[32][33];
    int n0 = bxx * 32, k0 = byy * 32;
    int tx = tid & 31, ty = tid >> 5;
    for (int j = 0; j < 4; j++)
      t[ty + j * 8][tx] = src[(size_t)(k0 + ty + j * 8) * N + n0 + tx];
    __syncthreads();
    for (int j = 0; j < 4; j++)
      dst[(size_t)(n0 + ty + j * 8) * DM + k0 + tx] = f2bf(t[tx][ty + j * 8]);
  } else if (blk < 18944) {
    int i = (blk - 18432) * 256 + tid;
    int p = i >> 6, d = i & 63;
    float inv_ts = powf(10000.0f, -(float)d * (1.0f / 64.0f));
    float sn, cs;
    sincosf((float)p * inv_ts, &sn, &cs);
    tbl[i] = make_float2(cs, sn);
  } else {
    int i = (blk - 18944) * 256 + tid;
    if (i < NQKV) biasqkv[i] = (i < DM) ? bq[i] : bkv[i - DM];
  }
}

// ---------------- 256xBN 8-phase bf16 GEMM (T2+T3+T4+T5); BN = 64*NIC ----------------
// 512 thr = 8 waves (2M x 4N). NIC=4: BN=256, 8 issues/tile, vmcnt(6).
// NIC=2: BN=128, 6 issues/tile, vmcnt(4). EPI=0: f32 C+bias. EPI=1: fused RoPE/scatter.

#define STA(buf, kt, q) gload_lds16(gA + (size_t)((q) * 32) * K + (kt), LW + (buf) * BUFB + ((q) * 32 + rowA) * 128)
#define STB(buf, kt, h) gload_lds16(gB + (size_t)((h) * 64) * K + (kt), LW + (buf) * BUFB + 32768 + ((h) * 64 + rowB) * 128)

#define RDB(buf) \
  _Pragma("unroll") for (int ni = 0; ni < NIC; ++ni) { \
    int row_ = (EPI == 1) ? (wc * 16 + ni * 64 + ln) : (wc * 16 * NIC + ni * 16 + ln); \
    const char* p_ = (const char*)LW + (buf) * BUFB + 32768 + row_ * 128; \
    bfr[ni][0] = *(const short8*)(p_ + coff0); \
    bfr[ni][1] = *(const short8*)(p_ + coff1); }

#define RDA(buf, q) \
  _Pragma("unroll") for (int m2 = 0; m2 < 2; ++m2) { \
    int row_ = wr * 128 + ((q) * 2 + m2) * 16 + ln; \
    const char* p_ = (const char*)LW + (buf) * BUFB + row_ * 128; \
    af[m2][0] = *(const short8*)(p_ + coff0); \
    af[m2][1] = *(const short8*)(p_ + coff1); }

#define MFQ(q) \
  _Pragma("unroll") for (int m2 = 0; m2 < 2; ++m2) \
  _Pragma("unroll") for (int ni = 0; ni < NIC; ++ni) { \
    acc[(q) * 2 + m2][ni] = __builtin_amdgcn_mfma_f32_16x16x32_bf16(af[m2][0], bfr[ni][0], acc[(q) * 2 + m2][ni], 0, 0, 0); \
    acc[(q) * 2 + m2][ni] = __builtin_amdgcn_mfma_f32_16x16x32_bf16(af[m2][1], bfr[ni][1], acc[(q) * 2 + m2][ni], 0, 0, 0); }

#define SYNC_IN() do { __builtin_amdgcn_sched_barrier(0); __builtin_amdgcn_s_barrier(); \
  asm volatile("s_waitcnt lgkmcnt(0)" ::: "memory"); __builtin_amdgcn_sched_barrier(0); \
  __builtin_amdgcn_s_setprio(1); } while (0)
#define SYNC_OUT() do { __builtin_amdgcn_s_setprio(0); __builtin_amdgcn_sched_barrier(0); \
  __builtin_amdgcn_s_barrier(); } while (0)
#define SYNC_OUT_VM6() do { __builtin_amdgcn_s_setprio(0); \
  asm volatile("s_waitcnt vmcnt(6)" ::: "memory"); __builtin_amdgcn_sched_barrier(0); \
  __builtin_amdgcn_s_barrier(); } while (0)
#define SYNC_OUT_VM4() do { __builtin_amdgcn_s_setprio(0); \
  asm volatile("s_waitcnt vmcnt(4)" ::: "memory"); __builtin_amdgcn_sched_barrier(0); \
  __builtin_amdgcn_s_barrier(); } while (0)

template <int EPI, int NIC>
__global__ __launch_bounds__(512, 2) void gemm8(
    const unsigned short* __restrict__ A, const unsigned short* __restrict__ Bt,
    const float* __restrict__ bias, const int* __restrict__ seq_pos,
    const float2* __restrict__ tbl,
    unsigned short* __restrict__ Qo, unsigned short* __restrict__ Ko,
    unsigned short* __restrict__ Vo, float* __restrict__ Cout,
    int nbx, int N, int K) {
  constexpr int BUFB = 32768 + NIC * 8192;   // bytes per LDS buffer (A 32K + B NIC*8K)
  __shared__ __align__(16) char lds[2 * BUFB];
  int tid = threadIdx.x, lane = tid & 63, w = tid >> 6;
  int wr = w >> 2, wc = w & 3;
  int lg = lane >> 4, ln = lane & 15;

  int bid = blockIdx.x;
  int cpx = gridDim.x >> 3;
  int swz = (bid & 7) * cpx + (bid >> 3);
  int by = swz / nbx, bx = swz - by * nbx;
  int m0 = by * 256, n0 = bx * (64 * NIC);

  int soff = ((lane & 7) ^ (lane >> 3)) << 3;
  const unsigned short* gA = A + (size_t)(m0 + ((w & 3) << 3) + ((w >> 2) << 7) + (lane >> 3)) * K + soff;
  const unsigned short* gB = Bt + (size_t)(n0 + (w << 3) + (lane >> 3)) * K + soff;
  char* LW = (char*)lds;
  int rowA = ((w & 3) << 3) + ((w >> 2) << 7);
  int rowB = (w << 3);
  int coff0 = ((lg)     ^ (ln & 7)) << 4;
  int coff1 = ((lg + 4) ^ (ln & 7)) << 4;

  f32x4 acc[8][NIC];
#pragma unroll
  for (int mi = 0; mi < 8; ++mi)
#pragma unroll
    for (int ni = 0; ni < NIC; ++ni) acc[mi][ni] = (f32x4){0, 0, 0, 0};

  short8 bfr[NIC][2], af[2][2];

  if constexpr (NIC == 4) {
    STB(0, 0, 0); STB(0, 0, 1); STB(0, 0, 2); STB(0, 0, 3);
    STA(0, 0, 0); STA(0, 0, 1); STA(0, 0, 2); STA(0, 0, 3);
    STB(1, 64, 0); STB(1, 64, 1); STB(1, 64, 2); STB(1, 64, 3);
    STA(1, 64, 0); STA(1, 64, 1);
    asm volatile("s_waitcnt vmcnt(6)" ::: "memory");
  } else {
    STB(0, 0, 0); STB(0, 0, 1);
    STA(0, 0, 0); STA(0, 0, 1); STA(0, 0, 2); STA(0, 0, 3);
    STB(1, 64, 0); STB(1, 64, 1);
    STA(1, 64, 0); STA(1, 64, 1);
    asm volatile("s_waitcnt vmcnt(4)" ::: "memory");
  }
  __builtin_amdgcn_sched_barrier(0);
  __builtin_amdgcn_s_barrier();

  for (int it = 0; it < (K >> 7); ++it) {
    int kt1  = it * 128 + 64;
    int ktn0 = (it * 128 + 128) & (K - 1);
    int ktn1 = (it * 128 + 192) & (K - 1);
    if constexpr (NIC == 4) {
      RDB(0); RDA(0, 0);
      STA(1, kt1, 2); STA(1, kt1, 3);
      SYNC_IN(); MFQ(0); SYNC_OUT();
      RDA(0, 1);
      STB(0, ktn0, 0); STB(0, ktn0, 1);
      SYNC_IN(); MFQ(1); SYNC_OUT();
      RDA(0, 2);
      STB(0, ktn0, 2); STB(0, ktn0, 3);
      SYNC_IN(); MFQ(2); SYNC_OUT();
      RDA(0, 3);
      STA(0, ktn0, 0); STA(0, ktn0, 1);
      SYNC_IN(); MFQ(3); SYNC_OUT_VM6();
      RDB(1); RDA(1, 0);
      STA(0, ktn0, 2); STA(0, ktn0, 3);
      SYNC_IN(); MFQ(0); SYNC_OUT();
      RDA(1, 1);
      STB(1, ktn1, 0); STB(1, ktn1, 1);
      SYNC_IN(); MFQ(1); SYNC_OUT();
      RDA(1, 2);
      STB(1, ktn1, 2); STB(1, ktn1, 3);
      SYNC_IN(); MFQ(2); SYNC_OUT();
      RDA(1, 3);
      STA(1, ktn1, 0); STA(1, ktn1, 1);
      SYNC_IN(); MFQ(3); SYNC_OUT_VM6();
    } else {
      RDB(0); RDA(0, 0);
      STA(1, kt1, 2); STA(1, kt1, 3);
      SYNC_IN(); MFQ(0); SYNC_OUT();
      RDA(0, 1);
      STB(0, ktn0, 0); STB(0, ktn0, 1);
      SYNC_IN(); MFQ(1); SYNC_OUT();
      RDA(0, 2);
      STA(0, ktn0, 0); STA(0, ktn0, 1);
      SYNC_IN(); MFQ(2); SYNC_OUT();
      RDA(0, 3);
      SYNC_IN(); MFQ(3); SYNC_OUT_VM4();
      RDB(1); RDA(1, 0);
      STA(0, ktn0, 2); STA(0, ktn0, 3);
      SYNC_IN(); MFQ(0); SYNC_OUT();
      RDA(1, 1);
      STB(1, ktn1, 0); STB(1, ktn1, 1);
      SYNC_IN(); MFQ(1); SYNC_OUT();
      RDA(1, 2);
      STA(1, ktn1, 0); STA(1, ktn1, 1);
      SYNC_IN(); MFQ(2); SYNC_OUT();
      RDA(1, 3);
      SYNC_IN(); MFQ(3); SYNC_OUT_VM4();
    }
  }
  asm volatile("s_waitcnt vmcnt(0)" ::: "memory");

  if constexpr (EPI == 0) {
#pragma unroll
    for (int mi = 0; mi < 8; ++mi) {
      int row = m0 + wr * 128 + mi * 16 + lg * 4;
#pragma unroll
      for (int ni = 0; ni < NIC; ++ni) {
        int col = n0 + wc * 16 * NIC + ni * 16 + ln;
        float bv = bias[col];
#pragma unroll
        for (int r = 0; r < 4; ++r)
          Cout[(size_t)(row + r) * N + col] = acc[mi][ni][r] + bv;
      }
    }
  } else {
    int d = wc * 16 + ln;
    float bv0 = bias[n0 + d],      bv1 = bias[n0 + d + 64];
    float bv2 = bias[n0 + d + 128], bv3 = bias[n0 + d + 192];
    int bI = m0 >> 11, s0 = m0 & (SEQ - 1);
    int nt = n0 >> 8;
    if (nt < 8) {
      unsigned short* qp0 = Qo + (size_t)(bI * NH + nt * 2) * SEQ * HD;
      unsigned short* qp1 = qp0 + (size_t)SEQ * HD;
#pragma unroll
      for (int mi = 0; mi < 8; ++mi) {
        int sl = wr * 128 + mi * 16 + lg * 4;
#pragma unroll
        for (int r = 0; r < 4; ++r) {
          int s = s0 + sl + r;
          int pos = seq_pos[bI * SEQ + s];
          float2 cs = tbl[pos * 64 + d];
          float x1 = acc[mi][0][r] + bv0, x2 = acc[mi][1][r] + bv1;
          float y1 = acc[mi][2][r] + bv2, y2 = acc[mi][3][r] + bv3;
          unsigned short* q0 = qp0 + (size_t)s * HD;
          q0[d]      = f2bf((x1 * cs.x - x2 * cs.y) * QSC);
          q0[d + 64] = f2bf((x2 * cs.x + x1 * cs.y) * QSC);
          unsigned short* q1 = qp1 + (size_t)s * HD;
          q1[d]      = f2bf((y1 * cs.x - y2 * cs.y) * QSC);
          q1[d + 64] = f2bf((y2 * cs.x + y1 * cs.y) * QSC);
        }
      }
    } else {
      int kvh = nt - 8;
      unsigned short* kp = Ko + (size_t)(bI * NKVH + kvh) * SEQ * HD;
      unsigned short* vp = Vo + (size_t)(bI * NKVH + kvh) * HD * SEQ;
#pragma unroll
      for (int mi = 0; mi < 8; ++mi) {
        int sl = wr * 128 + mi * 16 + lg * 4;
        ushort4 v0q, v1q;
#pragma unroll
        for (int r = 0; r < 4; ++r) {
          int s = s0 + sl + r;
          int pos = seq_pos[bI * SEQ + s];
          float2 cs = tbl[pos * 64 + d];
          float x1 = acc[mi][0][r] + bv0, x2 = acc[mi][1][r] + bv1;
          unsigned short* krow = kp + (size_t)s * HD;
          krow[d]      = f2bf(x1 * cs.x - x2 * cs.y);
          krow[d + 64] = f2bf(x2 * cs.x + x1 * cs.y);
          ((unsigned short*)&v0q)[r] = f2bf(acc[mi][2][r] + bv2);
          ((unsigned short*)&v1q)[r] = f2bf(acc[mi][3][r] + bv3);
        }
        *(ushort4*)(vp + (size_t)d * SEQ + s0 + sl)        = v0q;
        *(ushort4*)(vp + (size_t)(d + 64) * SEQ + s0 + sl) = v1q;
      }
    }
  }
}

// ---------------- causal GQA flash attention v6: swapped-QK^T 32x32 + K/V double-buffer ----------------
// grid (16, 32); 4 waves x 32 q-rows; KVB=64; 2-deep gload_lds pipeline with counted vmcnt(8).

__global__ __launch_bounds__(256, 2) void flash_attn(const unsigned short* __restrict__ Q,
                                                     const unsigned short* __restrict__ Kr,
                                                     const unsigned short* __restrict__ Vt,
                                                     const int* __restrict__ seq_pos,
                                                     unsigned short* __restrict__ X) {
  __shared__ __align__(16) unsigned short lds_k[2 * 64 * 128];   // [buf][kv][d]
  __shared__ __align__(16) unsigned short lds_v[2 * 128 * 64];   // [buf][d][kv]
  int tid = threadIdx.x, lane = tid & 63, w = tid >> 6;
  int hi = lane >> 5, q5 = lane & 31;
  int bh = blockIdx.y, b = bh >> 4, h = bh & 15, kvhh = h >> 2;
  int qtile = 15 - (int)blockIdx.x;   // LPT: longest first
  int qbase = qtile * 128;
  int q_global = qbase + w * 32 + q5;

  const unsigned short* kbase = Kr + ((size_t)(b * NKVH + kvhh)) * SEQ * HD;
  const unsigned short* vbase = Vt + ((size_t)(b * NKVH + kvhh)) * HD * SEQ;

  // staging: linear LDS dest, XOR-swizzled global source chunk (rule 21)
  const unsigned short* gks[4]; unsigned short* lks[4];
  const unsigned short* gvs[4]; unsigned short* lvs[4];
#pragma unroll
  for (int i = 0; i < 4; i++) {
    int kr = w * 16 + i * 4 + (lane >> 4);
    int kc = (lane & 15) ^ (kr & 7);
    gks[i] = kbase + (size_t)kr * HD + kc * 8;
    lks[i] = lds_k + (w * 16 + i * 4) * 128;
    int vr = w * 32 + i * 8 + (lane >> 3);
    int vc = (lane & 7) ^ (vr & 7);
    gvs[i] = vbase + (size_t)vr * SEQ + vc * 8;
    lvs[i] = lds_v + (w * 32 + i * 8) * 64;
  }

#define ISSUE(t, buf) do { int kv0_ = (t) * KVB; \
  _Pragma("unroll") for (int i_ = 0; i_ < 4; i_++) { \
    gload_lds16(gks[i_] + (size_t)kv0_ * HD, lks[i_] + (buf) * 8192); \
    gload_lds16(gvs[i_] + kv0_,              lvs[i_] + (buf) * 8192); } } while (0)

  int pm = max(seq_pos[b * SEQ + qbase + lane], seq_pos[b * SEQ + qbase + 64 + lane]);
#pragma unroll
  for (int o = 32; o; o >>= 1) { int t2 = __shfl_xor(pm, o); pm = pm > t2 ? pm : t2; }
  int ntiles = (pm + KVB) >> 6;          // >= 2 always (rows 0..127 present)
  if (ntiles > SEQ / KVB) ntiles = SEQ / KVB;

  int pos_q = seq_pos[b * SEQ + q_global];
  int wmin = pos_q;
#pragma unroll
  for (int o = 32; o; o >>= 1) { int t2 = __shfl_xor(wmin, o); wmin = wmin < t2 ? wmin : t2; }

  short8 qf[8];
  {
    const unsigned short* qp = Q + ((size_t)((b * NH + h) * SEQ + q_global)) * HD + hi * 8;
#pragma unroll
    for (int c = 0; c < 8; c++) qf[c] = *reinterpret_cast<const short8*>(qp + c * 16);
  }

  f32x16 acc[4];
#pragma unroll
  for (int db = 0; db < 4; db++)
#pragma unroll
    for (int r = 0; r < 16; ++r) acc[db][r] = 0.0f;
  float m_q = -1e30f, l_q = 0.0f;

  int swk = (q5 & 7) << 4;

  // prologue: stage tiles 0,1
  ISSUE(0, 0);
  ISSUE(1, 1);
  asm volatile("s_waitcnt vmcnt(8)" ::: "memory");
  __builtin_amdgcn_sched_barrier(0);
  __syncthreads();

  for (int t = 0; t < ntiles; t++) {
    int cur = t & 1;
    int kv0 = t * KVB;
    const char* kb = (const char*)(lds_k + cur * 8192);
    const char* vb = (const char*)(lds_v + cur * 8192);
    const char* kp0 = kb + q5 * 256;
    const char* kp1 = kp0 + 32 * 256;

    // QK^T: S^T[kv][q]
    f32x16 st0, st1;
#pragma unroll
    for (int r = 0; r < 16; ++r) { st0[r] = 0.0f; st1[r] = 0.0f; }
    __builtin_amdgcn_s_setprio(1);
#pragma unroll
    for (int c = 0; c < 8; c++) {
      short8 kf0 = *reinterpret_cast<const short8*>(kp0 + ((c * 32 + hi * 16) ^ swk));
      short8 kf1 = *reinterpret_cast<const short8*>(kp1 + ((c * 32 + hi * 16) ^ swk));
      st0 = __builtin_amdgcn_mfma_f32_32x32x16_bf16(kf0, qf[c], st0, 0, 0, 0);
      st1 = __builtin_amdgcn_mfma_f32_32x32x16_bf16(kf1, qf[c], st1, 0, 0, 0);
    }
    __builtin_amdgcn_s_setprio(0);

    if (kv0 + 63 > wmin) {
      int kvb = kv0 + 4 * hi;
#pragma unroll
      for (int r = 0; r < 16; ++r) {
        int kg = kvb + (r & 3) + 8 * (r >> 2);
        if (kg > pos_q)      st0[r] = -1e30f;
        if (kg + 32 > pos_q) st1[r] = -1e30f;
      }
    }

    float tm[16];
#pragma unroll
    for (int r = 0; r < 16; ++r) tm[r] = fmaxf(st0[r], st1[r]);
#pragma unroll
    for (int s = 8; s; s >>= 1)
#pragma unroll
      for (int r = 0; r < s; ++r) tm[r] = fmaxf(tm[r], tm[r + s]);
    float mx = fmaxf(tm[0], __shfl_xor(tm[0], 32));

    bool skip = (mx <= m_q + 8.0f) && (m_q > -1e29f);
    if (!__all((int)skip)) {
      float nm = fmaxf(m_q, mx);
      float corr = __expf(m_q - nm);
      m_q = nm; l_q *= corr;
#pragma unroll
      for (int db = 0; db < 4; db++)
#pragma unroll
        for (int r = 0; r < 16; ++r) acc[db][r] *= corr;
    }

    float sm[16];
#pragma unroll
    for (int r = 0; r < 16; ++r) {
      st0[r] = __expf(st0[r] - m_q);
      st1[r] = __expf(st1[r] - m_q);
      sm[r] = st0[r] + st1[r];
    }
#pragma unroll
    for (int s = 8; s; s >>= 1)
#pragma unroll
      for (int r = 0; r < s; ++r) sm[r] += sm[r + s];
    l_q += sm[0] + __shfl_xor(sm[0], 32);

    short8 pb[4];
#define MKFRAG(STV, B, OUT) { \
    unsigned a_ = cvtpk_bf16(STV[(B) + 0], STV[(B) + 1]); \
    unsigned b_ = cvtpk_bf16(STV[(B) + 2], STV[(B) + 3]); \
    unsigned c_ = cvtpk_bf16(STV[(B) + 4], STV[(B) + 5]); \
    unsigned d_ = cvtpk_bf16(STV[(B) + 6], STV[(B) + 7]); \
    uint2v r1_ = __builtin_amdgcn_permlane32_swap(a_, c_, false, false); \
    uint2v r2_ = __builtin_amdgcn_permlane32_swap(b_, d_, false, false); \
    union { unsigned u[4]; short8 s; } f_; \
    f_.u[0] = r1_[0]; f_.u[1] = r2_[0]; f_.u[2] = r1_[1]; f_.u[3] = r2_[1]; \
    OUT = f_.s; }
    MKFRAG(st0, 0, pb[0]);
    MKFRAG(st0, 8, pb[1]);
    MKFRAG(st1, 0, pb[2]);
    MKFRAG(st1, 8, pb[3]);
#undef MKFRAG

    __builtin_amdgcn_s_setprio(1);
#pragma unroll
    for (int db = 0; db < 4; db++) {
      const char* vr0 = vb + (db * 32 + q5) * 128;
#pragma unroll
      for (int tt = 0; tt < 4; tt++) {
        short8 vf = *reinterpret_cast<const short8*>(vr0 + ((tt * 32 + hi * 16) ^ swk));
        acc[db] = __builtin_amdgcn_mfma_f32_32x32x16_bf16(vf, pb[tt], acc[db], 0, 0, 0);
      }
    }
    __builtin_amdgcn_s_setprio(0);

    __syncthreads();                    // all waves done reading buf[cur]
    if (t + 2 < ntiles) {
      ISSUE(t + 2, cur);                // restage into buf[cur]
      asm volatile("s_waitcnt vmcnt(8)" ::: "memory");   // own t+1 loads landed
    } else {
      asm volatile("s_waitcnt vmcnt(0)" ::: "memory");
    }
    __builtin_amdgcn_sched_barrier(0);
    __syncthreads();                    // buf[cur^1] ready across waves
  }
#undef ISSUE

  float inv = l_q > 0.0f ? 1.0f / l_q : 0.0f;
  unsigned short* xp = X + ((size_t)(b * SEQ + q_global)) * DM + h * HD;
#pragma unroll
  for (int db = 0; db < 4; db++)
#pragma unroll
    for (int rq = 0; rq < 4; rq++) {
      int d = db * 32 + 4 * hi + 8 * rq;
      ushort4 o;
      unsigned short* op = (unsigned short*)&o;
#pragma unroll
      for (int j = 0; j < 4; j++) op[j] = f2bf(acc[db][rq * 4 + j] * inv);
      *(ushort4*)(xp + d) = o;
    }
}

// ---------------- launch ----------------

extern "C" void kernel_launch(void* const* d_in, const int* in_sizes, int n_in,
                              void* d_out, int out_size, void* d_ws, size_t ws_size,
                              hipStream_t stream) {
  const float* inputs  = (const float*)d_in[0];
  const int*   seq_pos = (const int*)d_in[1];
  const float* wq  = (const float*)d_in[2];
  const float* bq  = (const float*)d_in[3];
  const float* wkv = (const float*)d_in[4];
  const float* bkv = (const float*)d_in[5];
  const float* wo  = (const float*)d_in[6];
  const float* bo  = (const float*)d_in[7];
  float* out = (float*)d_out;

  char* ws = (char*)d_ws;
  unsigned short* Abf     = (unsigned short*)(ws + 0);          // 16.78 MB
  unsigned short* WqkvT   = (unsigned short*)(ws + 16777216);   // 12.58 MB
  unsigned short* WoT     = (unsigned short*)(ws + 29360128);   // 8.39 MB
  float*          biasqkv = (float*)(ws + 37748736);            // 12 KB
  float2*         tbl     = (float2*)(ws + 37761024);           // 1 MB
  unsigned short* Qr      = (unsigned short*)(ws + 38809600);   // 16.78 MB
  unsigned short* Kr      = (unsigned short*)(ws + 55586816);   // 4.19 MB
  unsigned short* Vt      = (unsigned short*)(ws + 59781120);   // 4.19 MB
  unsigned short* Xb      = (unsigned short*)(ws + 63975424);   // 16.78 MB (end ~80.8 MB)

  preamble<<<18956, 256, 0, stream>>>(inputs, wq, wkv, wo, bq, bkv,
                                      Abf, WqkvT, WoT, biasqkv, tbl);

  // QKV GEMM: 256x256 tiles, grid 16x12=192; fused RoPE/scatter epilogue
  gemm8<1, 4><<<(MROWS / 256) * (NQKV / 256), 512, 0, stream>>>(
      Abf, WqkvT, biasqkv, seq_pos, tbl, Qr, Kr, Vt, nullptr, NQKV / 256, NQKV, DM);

  flash_attn<<<dim3(16, NB * NH), 256, 0, stream>>>(Qr, Kr, Vt, seq_pos, Xb);

  // out-proj GEMM: 256x128 tiles, grid 16x16=256 (full CU fill), f32 out + bias
  gemm8<0, 2><<<(MROWS / 256) * (DM / 128), 512, 0, stream>>>(
      Xb, WoT, bo, nullptr, nullptr, nullptr, nullptr, nullptr, out, DM / 128, DM, DM);
}

// Round 8
// 291.241 us; speedup vs baseline: 1.5750x; 1.0079x over previous
//
#include <hip/hip_runtime.h>
#include <hip/hip_bf16.h>

// Problem dims
#define DM    2048
#define SEQ   2048
#define NB    2
#define NH    16
#define NKVH  4
#define HD    128
#define NQKV  3072   // 2048 q cols + 1024 kv cols
#define MROWS 4096   // B*S
#define KVB   64
#define QSC   0.08838834764831845f

using f32x4  = __attribute__((ext_vector_type(4))) float;
using f32x16 = __attribute__((ext_vector_type(16))) float;
using short8 = __attribute__((ext_vector_type(8))) short;
using ushort8 = __attribute__((ext_vector_type(8))) unsigned short;
using uint2v = __attribute__((ext_vector_type(2))) unsigned int;

static __device__ __forceinline__ unsigned short f2bf(float f) {
  __hip_bfloat16 h = __float2bfloat16(f);
  return *reinterpret_cast<unsigned short*>(&h);
}
static __device__ __forceinline__ unsigned cvtpk_bf16(float lo, float hi) {
  unsigned r;
  asm("v_cvt_pk_bf16_f32 %0, %1, %2" : "=v"(r) : "v"(lo), "v"(hi));
  return r;
}

// async global->LDS, 16B per lane; LDS dest is wave-uniform base + lane*16
typedef __attribute__((address_space(1))) const unsigned char as1_c;
typedef __attribute__((address_space(3))) unsigned char as3_c;
static __device__ __forceinline__ void gload_lds16(const void* g, void* l) {
  __builtin_amdgcn_global_load_lds((as1_c*)g, (as3_c*)l, 16, 0, 0);
}

// ---------------- fused preamble: bf16-convert, weight transposes, trig table, bias ----------------

__global__ __launch_bounds__(256) void preamble(
    const float* __restrict__ inputs, const float* __restrict__ wq,
    const float* __restrict__ wkv, const float* __restrict__ wo,
    const float* __restrict__ bq, const float* __restrict__ bkv,
    unsigned short* __restrict__ Abf, unsigned short* __restrict__ WqkvT,
    unsigned short* __restrict__ WoT, float* __restrict__ biasqkv,
    float2* __restrict__ tbl) {
  int blk = blockIdx.x, tid = threadIdx.x;
  if (blk < 8192) {
    int i = blk * 256 + tid;
    float4 v = reinterpret_cast<const float4*>(inputs)[i];
    ushort4 o;
    o.x = f2bf(v.x); o.y = f2bf(v.y); o.z = f2bf(v.z); o.w = f2bf(v.w);
    reinterpret_cast<ushort4*>(Abf)[i] = o;
  } else if (blk < 18432) {
    int rb = blk - 8192;
    int bxx = rb % 160, byy = rb / 160;
    const float* src; unsigned short* dst; int N;
    if (bxx < 64)      { src = wq;  dst = WqkvT;                     N = 2048; }
    else if (bxx < 96) { src = wkv; dst = WqkvT + (size_t)2048 * DM; N = 1024; bxx -= 64; }
    else               { src = wo;  dst = WoT;                       N = 2048; bxx -= 96; }
    __shared__ float t[32][33];
    int n0 = bxx * 32, k0 = byy * 32;
    int tx = tid & 31, ty = tid >> 5;
    for (int j = 0; j < 4; j++)
      t[ty + j * 8][tx] = src[(size_t)(k0 + ty + j * 8) * N + n0 + tx];
    __syncthreads();
    for (int j = 0; j < 4; j++)
      dst[(size_t)(n0 + ty + j * 8) * DM + k0 + tx] = f2bf(t[tx][ty + j * 8]);
  } else if (blk < 18944) {
    int i = (blk - 18432) * 256 + tid;
    int p = i >> 6, d = i & 63;
    float inv_ts = powf(10000.0f, -(float)d * (1.0f / 64.0f));
    float sn, cs;
    sincosf((float)p * inv_ts, &sn, &cs);
    tbl[i] = make_float2(cs, sn);
  } else {
    int i = (blk - 18944) * 256 + tid;
    if (i < NQKV) biasqkv[i] = (i < DM) ? bq[i] : bkv[i - DM];
  }
}

// ---------------- 256xBN 8-phase bf16 GEMM (T2+T3+T4+T5); BN = 64*NIC ----------------

#define STA(buf, kt, q) gload_lds16(gA + (size_t)((q) * 32) * K + (kt), LW + (buf) * BUFB + ((q) * 32 + rowA) * 128)
#define STB(buf, kt, h) gload_lds16(gB + (size_t)((h) * 64) * K + (kt), LW + (buf) * BUFB + 32768 + ((h) * 64 + rowB) * 128)

#define RDB(buf) \
  _Pragma("unroll") for (int ni = 0; ni < NIC; ++ni) { \
    int row_ = (EPI == 1) ? (wc * 16 + ni * 64 + ln) : (wc * 16 * NIC + ni * 16 + ln); \
    const char* p_ = (const char*)LW + (buf) * BUFB + 32768 + row_ * 128; \
    bfr[ni][0] = *(const short8*)(p_ + coff0); \
    bfr[ni][1] = *(const short8*)(p_ + coff1); }

#define RDA(buf, q) \
  _Pragma("unroll") for (int m2 = 0; m2 < 2; ++m2) { \
    int row_ = wr * 128 + ((q) * 2 + m2) * 16 + ln; \
    const char* p_ = (const char*)LW + (buf) * BUFB + row_ * 128; \
    af[m2][0] = *(const short8*)(p_ + coff0); \
    af[m2][1] = *(const short8*)(p_ + coff1); }

#define MFQ(q) \
  _Pragma("unroll") for (int m2 = 0; m2 < 2; ++m2) \
  _Pragma("unroll") for (int ni = 0; ni < NIC; ++ni) { \
    acc[(q) * 2 + m2][ni] = __builtin_amdgcn_mfma_f32_16x16x32_bf16(af[m2][0], bfr[ni][0], acc[(q) * 2 + m2][ni], 0, 0, 0); \
    acc[(q) * 2 + m2][ni] = __builtin_amdgcn_mfma_f32_16x16x32_bf16(af[m2][1], bfr[ni][1], acc[(q) * 2 + m2][ni], 0, 0, 0); }

#define SYNC_IN() do { __builtin_amdgcn_sched_barrier(0); __builtin_amdgcn_s_barrier(); \
  asm volatile("s_waitcnt lgkmcnt(0)" ::: "memory"); __builtin_amdgcn_sched_barrier(0); \
  __builtin_amdgcn_s_setprio(1); } while (0)
#define SYNC_OUT() do { __builtin_amdgcn_s_setprio(0); __builtin_amdgcn_sched_barrier(0); \
  __builtin_amdgcn_s_barrier(); } while (0)
#define SYNC_OUT_VM6() do { __builtin_amdgcn_s_setprio(0); \
  asm volatile("s_waitcnt vmcnt(6)" ::: "memory"); __builtin_amdgcn_sched_barrier(0); \
  __builtin_amdgcn_s_barrier(); } while (0)
#define SYNC_OUT_VM4() do { __builtin_amdgcn_s_setprio(0); \
  asm volatile("s_waitcnt vmcnt(4)" ::: "memory"); __builtin_amdgcn_sched_barrier(0); \
  __builtin_amdgcn_s_barrier(); } while (0)

template <int EPI, int NIC>
__global__ __launch_bounds__(512, 2) void gemm8(
    const unsigned short* __restrict__ A, const unsigned short* __restrict__ Bt,
    const float* __restrict__ bias, const int* __restrict__ seq_pos,
    const float2* __restrict__ tbl,
    unsigned short* __restrict__ Qo, unsigned short* __restrict__ Ko,
    unsigned short* __restrict__ Vo, float* __restrict__ Cout,
    int nbx, int N, int K) {
  constexpr int BUFB = 32768 + NIC * 8192;
  __shared__ __align__(16) char lds[2 * BUFB];
  int tid = threadIdx.x, lane = tid & 63, w = tid >> 6;
  int wr = w >> 2, wc = w & 3;
  int lg = lane >> 4, ln = lane & 15;

  int bid = blockIdx.x;
  int cpx = gridDim.x >> 3;
  int swz = (bid & 7) * cpx + (bid >> 3);
  int by = swz / nbx, bx = swz - by * nbx;
  int m0 = by * 256, n0 = bx * (64 * NIC);

  int soff = ((lane & 7) ^ (lane >> 3)) << 3;
  const unsigned short* gA = A + (size_t)(m0 + ((w & 3) << 3) + ((w >> 2) << 7) + (lane >> 3)) * K + soff;
  const unsigned short* gB = Bt + (size_t)(n0 + (w << 3) + (lane >> 3)) * K + soff;
  char* LW = (char*)lds;
  int rowA = ((w & 3) << 3) + ((w >> 2) << 7);
  int rowB = (w << 3);
  int coff0 = ((lg)     ^ (ln & 7)) << 4;
  int coff1 = ((lg + 4) ^ (ln & 7)) << 4;

  f32x4 acc[8][NIC];
#pragma unroll
  for (int mi = 0; mi < 8; ++mi)
#pragma unroll
    for (int ni = 0; ni < NIC; ++ni) acc[mi][ni] = (f32x4){0, 0, 0, 0};

  short8 bfr[NIC][2], af[2][2];

  if constexpr (NIC == 4) {
    STB(0, 0, 0); STB(0, 0, 1); STB(0, 0, 2); STB(0, 0, 3);
    STA(0, 0, 0); STA(0, 0, 1); STA(0, 0, 2); STA(0, 0, 3);
    STB(1, 64, 0); STB(1, 64, 1); STB(1, 64, 2); STB(1, 64, 3);
    STA(1, 64, 0); STA(1, 64, 1);
    asm volatile("s_waitcnt vmcnt(6)" ::: "memory");
  } else {
    STB(0, 0, 0); STB(0, 0, 1);
    STA(0, 0, 0); STA(0, 0, 1); STA(0, 0, 2); STA(0, 0, 3);
    STB(1, 64, 0); STB(1, 64, 1);
    STA(1, 64, 0); STA(1, 64, 1);
    asm volatile("s_waitcnt vmcnt(4)" ::: "memory");
  }
  __builtin_amdgcn_sched_barrier(0);
  __builtin_amdgcn_s_barrier();

  for (int it = 0; it < (K >> 7); ++it) {
    int kt1  = it * 128 + 64;
    int ktn0 = (it * 128 + 128) & (K - 1);
    int ktn1 = (it * 128 + 192) & (K - 1);
    if constexpr (NIC == 4) {
      RDB(0); RDA(0, 0);
      STA(1, kt1, 2); STA(1, kt1, 3);
      SYNC_IN(); MFQ(0); SYNC_OUT();
      RDA(0, 1);
      STB(0, ktn0, 0); STB(0, ktn0, 1);
      SYNC_IN(); MFQ(1); SYNC_OUT();
      RDA(0, 2);
      STB(0, ktn0, 2); STB(0, ktn0, 3);
      SYNC_IN(); MFQ(2); SYNC_OUT();
      RDA(0, 3);
      STA(0, ktn0, 0); STA(0, ktn0, 1);
      SYNC_IN(); MFQ(3); SYNC_OUT_VM6();
      RDB(1); RDA(1, 0);
      STA(0, ktn0, 2); STA(0, ktn0, 3);
      SYNC_IN(); MFQ(0); SYNC_OUT();
      RDA(1, 1);
      STB(1, ktn1, 0); STB(1, ktn1, 1);
      SYNC_IN(); MFQ(1); SYNC_OUT();
      RDA(1, 2);
      STB(1, ktn1, 2); STB(1, ktn1, 3);
      SYNC_IN(); MFQ(2); SYNC_OUT();
      RDA(1, 3);
      STA(1, ktn1, 0); STA(1, ktn1, 1);
      SYNC_IN(); MFQ(3); SYNC_OUT_VM6();
    } else {
      RDB(0); RDA(0, 0);
      STA(1, kt1, 2); STA(1, kt1, 3);
      SYNC_IN(); MFQ(0); SYNC_OUT();
      RDA(0, 1);
      STB(0, ktn0, 0); STB(0, ktn0, 1);
      SYNC_IN(); MFQ(1); SYNC_OUT();
      RDA(0, 2);
      STA(0, ktn0, 0); STA(0, ktn0, 1);
      SYNC_IN(); MFQ(2); SYNC_OUT();
      RDA(0, 3);
      SYNC_IN(); MFQ(3); SYNC_OUT_VM4();
      RDB(1); RDA(1, 0);
      STA(0, ktn0, 2); STA(0, ktn0, 3);
      SYNC_IN(); MFQ(0); SYNC_OUT();
      RDA(1, 1);
      STB(1, ktn1, 0); STB(1, ktn1, 1);
      SYNC_IN(); MFQ(1); SYNC_OUT();
      RDA(1, 2);
      STA(1, ktn1, 0); STA(1, ktn1, 1);
      SYNC_IN(); MFQ(2); SYNC_OUT();
      RDA(1, 3);
      SYNC_IN(); MFQ(3); SYNC_OUT_VM4();
    }
  }
  asm volatile("s_waitcnt vmcnt(0)" ::: "memory");

  if constexpr (EPI == 0) {
#pragma unroll
    for (int mi = 0; mi < 8; ++mi) {
      int row = m0 + wr * 128 + mi * 16 + lg * 4;
#pragma unroll
      for (int ni = 0; ni < NIC; ++ni) {
        int col = n0 + wc * 16 * NIC + ni * 16 + ln;
        float bv = bias[col];
#pragma unroll
        for (int r = 0; r < 4; ++r)
          Cout[(size_t)(row + r) * N + col] = acc[mi][ni][r] + bv;
      }
    }
  } else {
    int d = wc * 16 + ln;
    float bv0 = bias[n0 + d],      bv1 = bias[n0 + d + 64];
    float bv2 = bias[n0 + d + 128], bv3 = bias[n0 + d + 192];
    int bI = m0 >> 11, s0 = m0 & (SEQ - 1);
    int nt = n0 >> 8;
    if (nt < 8) {
      unsigned short* qp0 = Qo + (size_t)(bI * NH + nt * 2) * SEQ * HD;
      unsigned short* qp1 = qp0 + (size_t)SEQ * HD;
#pragma unroll
      for (int mi = 0; mi < 8; ++mi) {
        int sl = wr * 128 + mi * 16 + lg * 4;
#pragma unroll
        for (int r = 0; r < 4; ++r) {
          int s = s0 + sl + r;
          int pos = seq_pos[bI * SEQ + s];
          float2 cs = tbl[pos * 64 + d];
          float x1 = acc[mi][0][r] + bv0, x2 = acc[mi][1][r] + bv1;
          float y1 = acc[mi][2][r] + bv2, y2 = acc[mi][3][r] + bv3;
          unsigned short* q0 = qp0 + (size_t)s * HD;
          q0[d]      = f2bf((x1 * cs.x - x2 * cs.y) * QSC);
          q0[d + 64] = f2bf((x2 * cs.x + x1 * cs.y) * QSC);
          unsigned short* q1 = qp1 + (size_t)s * HD;
          q1[d]      = f2bf((y1 * cs.x - y2 * cs.y) * QSC);
          q1[d + 64] = f2bf((y2 * cs.x + y1 * cs.y) * QSC);
        }
      }
    } else {
      int kvh = nt - 8;
      unsigned short* kp = Ko + (size_t)(bI * NKVH + kvh) * SEQ * HD;
      unsigned short* vp = Vo + (size_t)(bI * NKVH + kvh) * HD * SEQ;
#pragma unroll
      for (int mi = 0; mi < 8; ++mi) {
        int sl = wr * 128 + mi * 16 + lg * 4;
        ushort4 v0q, v1q;
#pragma unroll
        for (int r = 0; r < 4; ++r) {
          int s = s0 + sl + r;
          int pos = seq_pos[bI * SEQ + s];
          float2 cs = tbl[pos * 64 + d];
          float x1 = acc[mi][0][r] + bv0, x2 = acc[mi][1][r] + bv1;
          unsigned short* krow = kp + (size_t)s * HD;
          krow[d]      = f2bf(x1 * cs.x - x2 * cs.y);
          krow[d + 64] = f2bf(x2 * cs.x + x1 * cs.y);
          ((unsigned short*)&v0q)[r] = f2bf(acc[mi][2][r] + bv2);
          ((unsigned short*)&v1q)[r] = f2bf(acc[mi][3][r] + bv3);
        }
        *(ushort4*)(vp + (size_t)d * SEQ + s0 + sl)        = v0q;
        *(ushort4*)(vp + (size_t)(d + 64) * SEQ + s0 + sl) = v1q;
      }
    }
  }
}

// ---------------- causal GQA flash attention v7: swapped-QK^T 32x32, K/V dbuf, RAW barriers ----------------
// v6 bug: __syncthreads() drains vmcnt(0) -> prefetch dead. v7 uses raw s_barrier
// (sched_barrier-fenced) + counted vmcnt(8), mirroring gemm8's verified pattern.
// Safety: ds_read results all consumed by MFMA before barrier#1 (reads retired ->
// WAR-safe restage); vmcnt(8) after ISSUE(t+2) retires own t+1 loads; barrier#2
// extends that to all waves before buf[cur^1] is read.

__global__ __launch_bounds__(256, 2) void flash_attn(const unsigned short* __restrict__ Q,
                                                     const unsigned short* __restrict__ Kr,
                                                     const unsigned short* __restrict__ Vt,
                                                     const int* __restrict__ seq_pos,
                                                     unsigned short* __restrict__ X) {
  __shared__ __align__(16) unsigned short lds_k[2 * 64 * 128];   // [buf][kv][d]
  __shared__ __align__(16) unsigned short lds_v[2 * 128 * 64];   // [buf][d][kv]
  int tid = threadIdx.x, lane = tid & 63, w = tid >> 6;
  int hi = lane >> 5, q5 = lane & 31;
  int bh = blockIdx.y, b = bh >> 4, h = bh & 15, kvhh = h >> 2;
  int qtile = 15 - (int)blockIdx.x;   // LPT: longest first
  int qbase = qtile * 128;
  int q_global = qbase + w * 32 + q5;

  const unsigned short* kbase = Kr + ((size_t)(b * NKVH + kvhh)) * SEQ * HD;
  const unsigned short* vbase = Vt + ((size_t)(b * NKVH + kvhh)) * HD * SEQ;

  const unsigned short* gks[4]; unsigned short* lks[4];
  const unsigned short* gvs[4]; unsigned short* lvs[4];
#pragma unroll
  for (int i = 0; i < 4; i++) {
    int kr = w * 16 + i * 4 + (lane >> 4);
    int kc = (lane & 15) ^ (kr & 7);
    gks[i] = kbase + (size_t)kr * HD + kc * 8;
    lks[i] = lds_k + (w * 16 + i * 4) * 128;
    int vr = w * 32 + i * 8 + (lane >> 3);
    int vc = (lane & 7) ^ (vr & 7);
    gvs[i] = vbase + (size_t)vr * SEQ + vc * 8;
    lvs[i] = lds_v + (w * 32 + i * 8) * 64;
  }

#define ISSUE(t, buf) do { int kv0_ = (t) * KVB; \
  _Pragma("unroll") for (int i_ = 0; i_ < 4; i_++) { \
    gload_lds16(gks[i_] + (size_t)kv0_ * HD, lks[i_] + (buf) * 8192); \
    gload_lds16(gvs[i_] + kv0_,              lvs[i_] + (buf) * 8192); } } while (0)
#define BAR() do { __builtin_amdgcn_sched_barrier(0); __builtin_amdgcn_s_barrier(); \
  __builtin_amdgcn_sched_barrier(0); } while (0)

  int pm = max(seq_pos[b * SEQ + qbase + lane], seq_pos[b * SEQ + qbase + 64 + lane]);
#pragma unroll
  for (int o = 32; o; o >>= 1) { int t2 = __shfl_xor(pm, o); pm = pm > t2 ? pm : t2; }
  int ntiles = (pm + KVB) >> 6;          // >= 2 always
  if (ntiles > SEQ / KVB) ntiles = SEQ / KVB;

  int pos_q = seq_pos[b * SEQ + q_global];
  int wmin = pos_q;
#pragma unroll
  for (int o = 32; o; o >>= 1) { int t2 = __shfl_xor(wmin, o); wmin = wmin < t2 ? wmin : t2; }

  short8 qf[8];
  {
    const unsigned short* qp = Q + ((size_t)((b * NH + h) * SEQ + q_global)) * HD + hi * 8;
#pragma unroll
    for (int c = 0; c < 8; c++) qf[c] = *reinterpret_cast<const short8*>(qp + c * 16);
  }

  f32x16 acc[4];
#pragma unroll
  for (int db = 0; db < 4; db++)
#pragma unroll
    for (int r = 0; r < 16; ++r) acc[db][r] = 0.0f;
  float m_q = -1e30f, l_q = 0.0f;

  int swk = (q5 & 7) << 4;

  // prologue: stage tiles 0,1; wait tile0 (own), publish via raw barrier
  ISSUE(0, 0);
  ISSUE(1, 1);
  asm volatile("s_waitcnt vmcnt(8)" ::: "memory");
  BAR();

  for (int t = 0; t < ntiles; t++) {
    int cur = t & 1;
    int kv0 = t * KVB;
    const char* kb = (const char*)(lds_k + cur * 8192);
    const char* vb = (const char*)(lds_v + cur * 8192);
    const char* kp0 = kb + q5 * 256;
    const char* kp1 = kp0 + 32 * 256;

    // QK^T: S^T[kv][q]
    f32x16 st0, st1;
#pragma unroll
    for (int r = 0; r < 16; ++r) { st0[r] = 0.0f; st1[r] = 0.0f; }
    __builtin_amdgcn_s_setprio(1);
#pragma unroll
    for (int c = 0; c < 8; c++) {
      short8 kf0 = *reinterpret_cast<const short8*>(kp0 + ((c * 32 + hi * 16) ^ swk));
      short8 kf1 = *reinterpret_cast<const short8*>(kp1 + ((c * 32 + hi * 16) ^ swk));
      st0 = __builtin_amdgcn_mfma_f32_32x32x16_bf16(kf0, qf[c], st0, 0, 0, 0);
      st1 = __builtin_amdgcn_mfma_f32_32x32x16_bf16(kf1, qf[c], st1, 0, 0, 0);
    }
    __builtin_amdgcn_s_setprio(0);

    if (kv0 + 63 > wmin) {
      int kvb = kv0 + 4 * hi;
#pragma unroll
      for (int r = 0; r < 16; ++r) {
        int kg = kvb + (r & 3) + 8 * (r >> 2);
        if (kg > pos_q)      st0[r] = -1e30f;
        if (kg + 32 > pos_q) st1[r] = -1e30f;
      }
    }

    float tm[16];
#pragma unroll
    for (int r = 0; r < 16; ++r) tm[r] = fmaxf(st0[r], st1[r]);
#pragma unroll
    for (int s = 8; s; s >>= 1)
#pragma unroll
      for (int r = 0; r < s; ++r) tm[r] = fmaxf(tm[r], tm[r + s]);
    float mx = fmaxf(tm[0], __shfl_xor(tm[0], 32));

    bool skip = (mx <= m_q + 8.0f) && (m_q > -1e29f);
    if (!__all((int)skip)) {
      float nm = fmaxf(m_q, mx);
      float corr = __expf(m_q - nm);
      m_q = nm; l_q *= corr;
#pragma unroll
      for (int db = 0; db < 4; db++)
#pragma unroll
        for (int r = 0; r < 16; ++r) acc[db][r] *= corr;
    }

    float sm[16];
#pragma unroll
    for (int r = 0; r < 16; ++r) {
      st0[r] = __expf(st0[r] - m_q);
      st1[r] = __expf(st1[r] - m_q);
      sm[r] = st0[r] + st1[r];
    }
#pragma unroll
    for (int s = 8; s; s >>= 1)
#pragma unroll
      for (int r = 0; r < s; ++r) sm[r] += sm[r + s];
    l_q += sm[0] + __shfl_xor(sm[0], 32);

    short8 pb[4];
#define MKFRAG(STV, B, OUT) { \
    unsigned a_ = cvtpk_bf16(STV[(B) + 0], STV[(B) + 1]); \
    unsigned b_ = cvtpk_bf16(STV[(B) + 2], STV[(B) + 3]); \
    unsigned c_ = cvtpk_bf16(STV[(B) + 4], STV[(B) + 5]); \
    unsigned d_ = cvtpk_bf16(STV[(B) + 6], STV[(B) + 7]); \
    uint2v r1_ = __builtin_amdgcn_permlane32_swap(a_, c_, false, false); \
    uint2v r2_ = __builtin_amdgcn_permlane32_swap(b_, d_, false, false); \
    union { unsigned u[4]; short8 s; } f_; \
    f_.u[0] = r1_[0]; f_.u[1] = r2_[0]; f_.u[2] = r1_[1]; f_.u[3] = r2_[1]; \
    OUT = f_.s; }
    MKFRAG(st0, 0, pb[0]);
    MKFRAG(st0, 8, pb[1]);
    MKFRAG(st1, 0, pb[2]);
    MKFRAG(st1, 8, pb[3]);
#undef MKFRAG

    __builtin_amdgcn_s_setprio(1);
#pragma unroll
    for (int db = 0; db < 4; db++) {
      const char* vr0 = vb + (db * 32 + q5) * 128;
#pragma unroll
      for (int tt = 0; tt < 4; tt++) {
        short8 vf = *reinterpret_cast<const short8*>(vr0 + ((tt * 32 + hi * 16) ^ swk));
        acc[db] = __builtin_amdgcn_mfma_f32_32x32x16_bf16(vf, pb[tt], acc[db], 0, 0, 0);
      }
    }
    __builtin_amdgcn_s_setprio(0);

    // barrier#1 (raw): all waves done reading buf[cur] -> restage is WAR-safe
    BAR();
    if (t + 2 < ntiles) {
      ISSUE(t + 2, cur);
      asm volatile("s_waitcnt vmcnt(8)" ::: "memory");   // own t+1 loads retired
    } else {
      asm volatile("s_waitcnt vmcnt(0)" ::: "memory");   // tail drain
    }
    __builtin_amdgcn_sched_barrier(0);
    // barrier#2 (raw): every wave's t+1 loads retired -> buf[cur^1] complete
    BAR();
  }
#undef ISSUE
#undef BAR

  float inv = l_q > 0.0f ? 1.0f / l_q : 0.0f;
  unsigned short* xp = X + ((size_t)(b * SEQ + q_global)) * DM + h * HD;
#pragma unroll
  for (int db = 0; db < 4; db++)
#pragma unroll
    for (int rq = 0; rq < 4; rq++) {
      int d = db * 32 + 4 * hi + 8 * rq;
      ushort4 o;
      unsigned short* op = (unsigned short*)&o;
#pragma unroll
      for (int j = 0; j < 4; j++) op[j] = f2bf(acc[db][rq * 4 + j] * inv);
      *(ushort4*)(xp + d) = o;
    }
}

// ---------------- launch ----------------

extern "C" void kernel_launch(void* const* d_in, const int* in_sizes, int n_in,
                              void* d_out, int out_size, void* d_ws, size_t ws_size,
                              hipStream_t stream) {
  const float* inputs  = (const float*)d_in[0];
  const int*   seq_pos = (const int*)d_in[1];
  const float* wq  = (const float*)d_in[2];
  const float* bq  = (const float*)d_in[3];
  const float* wkv = (const float*)d_in[4];
  const float* bkv = (const float*)d_in[5];
  const float* wo  = (const float*)d_in[6];
  const float* bo  = (const float*)d_in[7];
  float* out = (float*)d_out;

  char* ws = (char*)d_ws;
  unsigned short* Abf     = (unsigned short*)(ws + 0);          // 16.78 MB
  unsigned short* WqkvT   = (unsigned short*)(ws + 16777216);   // 12.58 MB
  unsigned short* WoT     = (unsigned short*)(ws + 29360128);   // 8.39 MB
  float*          biasqkv = (float*)(ws + 37748736);            // 12 KB
  float2*         tbl     = (float2*)(ws + 37761024);           // 1 MB
  unsigned short* Qr      = (unsigned short*)(ws + 38809600);   // 16.78 MB
  unsigned short* Kr      = (unsigned short*)(ws + 55586816);   // 4.19 MB
  unsigned short* Vt      = (unsigned short*)(ws + 59781120);   // 4.19 MB
  unsigned short* Xb      = (unsigned short*)(ws + 63975424);   // 16.78 MB (end ~80.8 MB)

  preamble<<<18956, 256, 0, stream>>>(inputs, wq, wkv, wo, bq, bkv,
                                      Abf, WqkvT, WoT, biasqkv, tbl);

  gemm8<1, 4><<<(MROWS / 256) * (NQKV / 256), 512, 0, stream>>>(
      Abf, WqkvT, biasqkv, seq_pos, tbl, Qr, Kr, Vt, nullptr, NQKV / 256, NQKV, DM);

  flash_attn<<<dim3(16, NB * NH), 256, 0, stream>>>(Qr, Kr, Vt, seq_pos, Xb);

  gemm8<0, 2><<<(MROWS / 256) * (DM / 128), 512, 0, stream>>>(
      Xb, WoT, bo, nullptr, nullptr, nullptr, nullptr, nullptr, out, DM / 128, DM, DM);
}